// Round 3
// baseline (1491.585 us; speedup 1.0000x reference)
//
#include <hip/hip_runtime.h>

#define DIMN 2048
#define NH 16
#define HDIM 128

typedef __attribute__((ext_vector_type(4))) float f32x4;
typedef __attribute__((ext_vector_type(8))) __bf16 bfx8;
typedef __attribute__((ext_vector_type(8))) unsigned short u16x8;

__device__ __forceinline__ unsigned short f2bf(float f){
  unsigned u = __builtin_bit_cast(unsigned, f);
  u += 0x7fffu + ((u >> 16) & 1u);
  return (unsigned short)(u >> 16);
}

__device__ __forceinline__ void gl_lds16(const void* g, void* l){
  __builtin_amdgcn_global_load_lds((const __attribute__((address_space(1))) void*)g,
                                   (__attribute__((address_space(3))) void*)l, 16, 0, 0);
}

#define MFMA16(a,b,c) __builtin_amdgcn_mfma_f32_16x16x32_bf16((a),(b),(c),0,0,0)

// ---------------- elementwise f32 -> bf16 cast ----------------
__global__ __launch_bounds__(256) void cast_bf16_kernel(const float* __restrict__ in,
                                                        unsigned short* __restrict__ out, int n8){
  int i = blockIdx.x*256 + threadIdx.x;
  if (i >= n8) return;
  const float4* p = (const float4*)(in + (size_t)i*8);
  float4 a = p[0], b = p[1];
  u16x8 o;
  o[0]=f2bf(a.x); o[1]=f2bf(a.y); o[2]=f2bf(a.z); o[3]=f2bf(a.w);
  o[4]=f2bf(b.x); o[5]=f2bf(b.y); o[6]=f2bf(b.z); o[7]=f2bf(b.w);
  *(u16x8*)(out + (size_t)i*8) = o;
}

// ---------------- k_cache (CACHE,H,HD) f32 -> kb[h][k][d] bf16 ----------------
__global__ __launch_bounds__(256) void kcache_kernel(const float* __restrict__ kc,
                                                     unsigned short* __restrict__ kb,
                                                     int R, int L_){
  const int gid = blockIdx.x*256 + threadIdx.x;
  if (gid >= R*256) return;
  const size_t idx = (size_t)gid * 8;
  const int k   = (int)(idx >> 11);
  const int rem = (int)(idx & 2047);
  const int hh  = rem >> 7, d = rem & 127;
  const float4* p = (const float4*)(kc + idx);
  float4 a = p[0], b = p[1];
  u16x8 o;
  o[0]=f2bf(a.x); o[1]=f2bf(a.y); o[2]=f2bf(a.z); o[3]=f2bf(a.w);
  o[4]=f2bf(b.x); o[5]=f2bf(b.y); o[6]=f2bf(b.z); o[7]=f2bf(b.w);
  *(u16x8*)(kb + (size_t)hh*L_*HDIM + (size_t)k*HDIM + d) = o;
}

// ---------------- (R,H,HD) f32 -> vt[h][d][koff+k] bf16 (transpose) ----------------
__global__ __launch_bounds__(256) void vtrans_kernel(const float* __restrict__ src,
                                                     unsigned short* __restrict__ vt,
                                                     int R, int koff, int L_){
  __shared__ __align__(16) unsigned short tile[32][72];
  const int kb0 = blockIdx.x * 64, db0 = blockIdx.y * 32, hh = blockIdx.z;
  const int t = threadIdx.x;
  const int kk = t >> 2, dd = (t & 3) * 8;
  const int k = kb0 + kk;
  if (k < R){
    const float* p = src + (size_t)k*DIMN + hh*HDIM + db0 + dd;
    float4 a = ((const float4*)p)[0], b = ((const float4*)p)[1];
    tile[dd+0][kk] = f2bf(a.x); tile[dd+1][kk] = f2bf(a.y);
    tile[dd+2][kk] = f2bf(a.z); tile[dd+3][kk] = f2bf(a.w);
    tile[dd+4][kk] = f2bf(b.x); tile[dd+5][kk] = f2bf(b.y);
    tile[dd+6][kk] = f2bf(b.z); tile[dd+7][kk] = f2bf(b.w);
  }
  __syncthreads();
  const int d = t >> 3, k0 = (t & 7) * 8;
  unsigned short* dst = vt + (size_t)hh*HDIM*L_ + (size_t)(db0+d)*L_ + koff + kb0 + k0;
  if (kb0 + k0 + 8 <= R){
    *(u16x8*)dst = *(const u16x8*)&tile[d][k0];
  } else {
    #pragma unroll
    for (int e=0;e<8;++e) if (kb0 + k0 + e < R) dst[e] = tile[d][k0+e];
  }
}

// ---------------- fused rmsnorm + interleaved RoPE, bf16 head-major out ----------------
__global__ __launch_bounds__(256) void norm_rope_kernel(const float* __restrict__ lin,
    const float* __restrict__ g, const float* __restrict__ freqs, const int* __restrict__ cur,
    unsigned short* __restrict__ out, int S_, size_t head_stride, int row_off){
  const int q = blockIdx.x, t = threadIdx.x;
  const float* row = lin + (size_t)q * DIMN;
  float4 v0 = ((const float4*)row)[t*2];
  float4 v1 = ((const float4*)row)[t*2+1];
  float x[8] = {v0.x, v0.y, v0.z, v0.w, v1.x, v1.y, v1.z, v1.w};
  float ss = 0.f;
  #pragma unroll
  for (int e=0;e<8;++e) ss += x[e]*x[e];
  for (int m=1;m<64;m<<=1) ss += __shfl_xor(ss, m);
  __shared__ float red[4];
  if ((t & 63) == 0) red[t>>6] = ss;
  __syncthreads();
  const float tot = red[0]+red[1]+red[2]+red[3];
  const float rstd = rsqrtf(tot * (1.0f/2048.0f) + 1e-6f);
  const int n0 = t*8;
  float xr[8];
  #pragma unroll
  for (int e=0;e<8;++e) xr[e] = x[e] * rstd * g[n0+e];
  const int pos = cur[0] + q;
  const int hh = n0 >> 7, d0 = n0 & 127;
  const float* fr = freqs + (size_t)pos * HDIM;
  float o[8];
  #pragma unroll
  for (int p=0;p<4;++p){
    const int j = (d0>>1) + p;
    const float c = fr[j], s = fr[64+j];
    o[2*p]   = xr[2*p]*c - xr[2*p+1]*s;
    o[2*p+1] = xr[2*p+1]*c + xr[2*p]*s;
  }
  u16x8 ov;
  #pragma unroll
  for (int e=0;e<8;++e) ov[e] = f2bf(o[e]);
  *(u16x8*)(out + (size_t)hh*head_stride + (size_t)(q+row_off)*HDIM + d0) = ov;
}

// ---------------- C[M,N] = A[M,K] * B[N,K]^T + bias, bf16 in fp32 out ----------------
__global__ __launch_bounds__(256,2) void gemm_bt(const unsigned short* __restrict__ A,
    const unsigned short* __restrict__ B, const float* __restrict__ bias,
    float* __restrict__ C, int M, int N, int K){
  __shared__ __align__(16) unsigned short As[128*64];
  __shared__ __align__(16) unsigned short Bs[128*64];
  const int t = threadIdx.x;
  const int w = t >> 6, lane = t & 63, lh = lane >> 4, ll = lane & 15;
  const int wr = w >> 1, wc = w & 1;
  const int m0 = blockIdx.y * 128, n0 = blockIdx.x * 128;
  const int srow = t >> 3;
  const int scb  = (t & 7) * 16;
  const int swc  = (scb ^ ((srow & 7) << 4)) >> 1;
  int arow[4]; size_t brow[4];
  #pragma unroll
  for (int c=0;c<4;++c){
    int r = m0 + c*32 + srow; if (r >= M) r = M-1;
    arow[c] = r;
    brow[c] = (size_t)(n0 + c*32 + srow);
  }
  const int xsw = (ll & 7) << 4;
  f32x4 acc[4][4] = {};
  const int nk = K >> 6;
  for (int kt = 0; kt < nk; ++kt){
    const int k0 = kt << 6;
    #pragma unroll
    for (int c=0;c<4;++c){
      gl_lds16(A + (size_t)arow[c]*K + k0 + swc, (char*)As + c*4096 + w*1024);
      gl_lds16(B + brow[c]*K       + k0 + swc, (char*)Bs + c*4096 + w*1024);
    }
    asm volatile("s_waitcnt vmcnt(0)" ::: "memory");
    __syncthreads();
    #pragma unroll
    for (int kk=0;kk<2;++kk){
      const int cb = kk*64 + lh*16;
      bfx8 a[4], b[4];
      #pragma unroll
      for (int i=0;i<4;++i)
        a[i] = *(const bfx8*)((const char*)As + (wr*64 + i*16 + ll)*128 + (cb ^ xsw));
      #pragma unroll
      for (int j=0;j<4;++j)
        b[j] = *(const bfx8*)((const char*)Bs + (wc*64 + j*16 + ll)*128 + (cb ^ xsw));
      #pragma unroll
      for (int i=0;i<4;++i)
        #pragma unroll
        for (int j=0;j<4;++j)
          acc[i][j] = MFMA16(a[i], b[j], acc[i][j]);
    }
    __syncthreads();
  }
  #pragma unroll
  for (int i=0;i<4;++i){
    #pragma unroll
    for (int j=0;j<4;++j){
      const int col = n0 + wc*64 + j*16 + ll;
      const float bb = bias[col];
      #pragma unroll
      for (int r=0;r<4;++r){
        const int row = m0 + wr*64 + i*16 + lh*4 + r;
        if (row < M) C[(size_t)row*N + col] = acc[i][j][r] + bb;
      }
    }
  }
}

// ---------------- flash attention with KV-split partials ----------------
// 4 waves, 128 q-rows/block, 64-key tiles, blockIdx.z = KV split index.
// LDS 32KB (P overlays each wave's quarter of Ks after QK^T; extra barrier).
// T13 defer-max with -1e20 row-max floor (robust vs fully-masked tiles).
__global__ __launch_bounds__(256,4) void attn_kernel(const unsigned short* __restrict__ Q,
    const unsigned short* __restrict__ K, const unsigned short* __restrict__ VT,
    unsigned short* __restrict__ O, float* __restrict__ pacc, float* __restrict__ pml,
    int S_, int L_, int CLn, int nsplit){
  __shared__ __align__(16) unsigned short Ks[64*128];
  __shared__ __align__(16) unsigned short Vs[128*64];
  const int hh = blockIdx.y;
  const int q0 = blockIdx.x * 128;
  const int z  = blockIdx.z;
  const int t = threadIdx.x, w = t >> 6, lane = t & 63, lh = lane >> 4, ll = lane & 15;
  const int xsw = (ll & 7) << 4;
  char* Pw = (char*)Ks + w*4096;     // wave-private P buffer overlaying Ks quarter
  const unsigned short* Qh = Q  + (size_t)hh*S_*HDIM;
  const unsigned short* Kh = K  + (size_t)hh*L_*HDIM;
  const unsigned short* Vh = VT + (size_t)hh*HDIM*L_;
  bfx8 qf[2][4];
  #pragma unroll
  for (int i=0;i<2;++i){
    int qr = q0 + w*32 + i*16 + ll; if (qr >= S_) qr = S_ - 1;
    #pragma unroll
    for (int kk=0;kk<4;++kk)
      qf[i][kk] = *(const bfx8*)(Qh + (size_t)qr*HDIM + kk*32 + lh*8);
  }
  f32x4 acc[2][8] = {};
  float m_st[2][4], l_st[2][4];
  #pragma unroll
  for (int i=0;i<2;++i)
    #pragma unroll
    for (int r=0;r<4;++r){ m_st[i][r] = -1e20f; l_st[i][r] = 0.f; }
  const int wrow0 = q0 + w*32;
  int qlast = q0 + 127; if (qlast >= S_) qlast = S_ - 1;
  const int kend = CLn + qlast + 1;
  const int nt = (kend + 63) >> 6;
  const int tps = (nt + nsplit - 1) / nsplit;
  const int t0 = z * tps;
  int t1 = t0 + tps; if (t1 > nt) t1 = nt;
  const float scale = 0.08838834764831845f;
  const int ksrow = t >> 4, kchunk = t & 15;
  const int vsrow = t >> 3, vchunk = t & 7;

  for (int kt = t0; kt < t1; ++kt){
    const int kv0 = kt << 6;
    u16x8 kreg[4], vreg[4];
    #pragma unroll
    for (int c=0;c<4;++c){
      int krow = kv0 + c*16 + ksrow; if (krow >= L_) krow = L_ - 1;
      kreg[c] = *(const u16x8*)(Kh + (size_t)krow*HDIM + kchunk*8);
      int vcol = kv0 + vchunk*8; if (vcol > L_ - 8) vcol = L_ - 8;
      vreg[c] = *(const u16x8*)(Vh + (size_t)(c*32 + vsrow)*L_ + vcol);
    }
    __syncthreads();   // all waves done reading prev tile's Ks(P)/Vs
    #pragma unroll
    for (int c=0;c<4;++c){
      *(u16x8*)((char*)Ks + (c*16 + ksrow)*256 + ((kchunk*16) ^ ((ksrow & 7) << 4))) = kreg[c];
      *(u16x8*)((char*)Vs + (c*32 + vsrow)*128 + ((vchunk*16) ^ ((vsrow & 7) << 4))) = vreg[c];
    }
    __syncthreads();
    // QK^T
    f32x4 sc[2][4] = {};
    #pragma unroll
    for (int kk=0;kk<4;++kk){
      const int cb = kk*64 + lh*16;
      #pragma unroll
      for (int j=0;j<4;++j){
        bfx8 kf = *(const bfx8*)((const char*)Ks + (j*16 + ll)*256 + (cb ^ xsw));
        sc[0][j] = MFMA16(qf[0][kk], kf, sc[0][j]);
        sc[1][j] = MFMA16(qf[1][kk], kf, sc[1][j]);
      }
    }
    // scale + causal mask
    const bool needmask = (kv0 + 63 > CLn + wrow0);
    #pragma unroll
    for (int i=0;i<2;++i)
      #pragma unroll
      for (int j=0;j<4;++j)
        #pragma unroll
        for (int r=0;r<4;++r){
          float v = sc[i][j][r] * scale;
          if (needmask){
            const int qrow = wrow0 + i*16 + lh*4 + r;
            const int key  = kv0 + j*16 + ll;
            if (key > CLn + qrow) v = -1e30f;
          }
          sc[i][j][r] = v;
        }
    // row max (floored) + defer-max decision
    float pmax[2][4];
    float mdiff = 0.f;
    #pragma unroll
    for (int i=0;i<2;++i){
      #pragma unroll
      for (int r=0;r<4;++r){
        float m = fmaxf(fmaxf(sc[i][0][r], sc[i][1][r]), fmaxf(sc[i][2][r], sc[i][3][r]));
        m = fmaxf(m, __shfl_xor(m, 1));
        m = fmaxf(m, __shfl_xor(m, 2));
        m = fmaxf(m, __shfl_xor(m, 4));
        m = fmaxf(m, __shfl_xor(m, 8));
        m = fmaxf(m, -1e20f);
        pmax[i][r] = m;
        mdiff = fmaxf(mdiff, m - m_st[i][r]);
      }
    }
    const bool skip = __all(mdiff <= 8.0f);
    if (!skip){
      #pragma unroll
      for (int i=0;i<2;++i){
        #pragma unroll
        for (int r=0;r<4;++r){
          const float mn = fmaxf(m_st[i][r], pmax[i][r]);
          const float corr = __expf(m_st[i][r] - mn);
          m_st[i][r] = mn;
          l_st[i][r] *= corr;
          #pragma unroll
          for (int jn=0;jn<8;++jn) acc[i][jn][r] *= corr;
        }
      }
    }
    // P = exp(sc - m), row-sum
    #pragma unroll
    for (int i=0;i<2;++i){
      #pragma unroll
      for (int r=0;r<4;++r){
        float rs = 0.f;
        #pragma unroll
        for (int j=0;j<4;++j){
          const float pv = __expf(sc[i][j][r] - m_st[i][r]);
          sc[i][j][r] = pv;
          rs += pv;
        }
        rs += __shfl_xor(rs, 1);
        rs += __shfl_xor(rs, 2);
        rs += __shfl_xor(rs, 4);
        rs += __shfl_xor(rs, 8);
        l_st[i][r] += rs;
      }
    }
    __syncthreads();   // all waves done reading K data from Ks; P may overlay
    #pragma unroll
    for (int i=0;i<2;++i)
      #pragma unroll
      for (int j=0;j<4;++j)
        #pragma unroll
        for (int r=0;r<4;++r){
          const int prow = i*16 + lh*4 + r;
          const int pcb  = (j*16 + ll)*2;
          *(unsigned short*)(Pw + prow*128 + (pcb ^ ((prow & 7) << 4))) = f2bf(sc[i][j][r]);
        }
    // PV
    #pragma unroll
    for (int kk=0;kk<2;++kk){
      const int cb = kk*64 + lh*16;
      bfx8 af0 = *(const bfx8*)(Pw + (ll)*128      + (cb ^ xsw));
      bfx8 af1 = *(const bfx8*)(Pw + (16 + ll)*128 + (cb ^ xsw));
      #pragma unroll
      for (int jn=0;jn<8;++jn){
        bfx8 vf = *(const bfx8*)((const char*)Vs + (jn*16 + ll)*128 + (cb ^ xsw));
        acc[0][jn] = MFMA16(af0, vf, acc[0][jn]);
        acc[1][jn] = MFMA16(af1, vf, acc[1][jn]);
      }
    }
  }
  // epilogue
  if (nsplit == 1){
    #pragma unroll
    for (int i=0;i<2;++i){
      #pragma unroll
      for (int r=0;r<4;++r){
        const float inv = 1.0f / l_st[i][r];
        const int qr = wrow0 + i*16 + lh*4 + r;
        if (qr < S_){
          #pragma unroll
          for (int jn=0;jn<8;++jn)
            O[(size_t)qr*DIMN + hh*HDIM + jn*16 + ll] = f2bf(acc[i][jn][r]*inv);
        }
      }
    }
  } else {
    #pragma unroll
    for (int i=0;i<2;++i){
      #pragma unroll
      for (int r=0;r<4;++r){
        const int qr = wrow0 + i*16 + lh*4 + r;
        if (qr < S_){
          const size_t rid = ((size_t)z*NH + hh)*S_ + qr;
          float* dst = pacc + rid*128;
          #pragma unroll
          for (int jn=0;jn<8;++jn) dst[jn*16 + ll] = acc[i][jn][r];
          if (ll == 0){
            pml[rid*2]   = m_st[i][r];
            pml[rid*2+1] = l_st[i][r];
          }
        }
      }
    }
  }
}

// ---------------- combine partials -> ob bf16 ----------------
__global__ __launch_bounds__(256) void combine_kernel(const float* __restrict__ pacc,
    const float* __restrict__ pml, unsigned short* __restrict__ ob, int S_, int nsplit){
  const int t = threadIdx.x;
  const int rid = blockIdx.x*2 + (t >> 7);   // hh*S_+q
  if (rid >= S_*NH) return;
  const int d = t & 127;
  const int hh = rid / S_;
  const int q  = rid - hh*S_;
  float M = -1e20f;
  for (int s=0; s<nsplit; ++s)
    M = fmaxf(M, pml[((size_t)s*NH*S_ + rid)*2]);
  float lt = 0.f, o = 0.f;
  for (int s=0; s<nsplit; ++s){
    const float m = pml[((size_t)s*NH*S_ + rid)*2];
    const float l = pml[((size_t)s*NH*S_ + rid)*2 + 1];
    const float wgt = __expf(m - M);
    lt += l * wgt;
    o  += pacc[((size_t)s*NH*S_ + rid)*128 + d] * wgt;
  }
  if (lt == 0.f) lt = 1.f;
  ob[(size_t)q*DIMN + hh*HDIM + d] = f2bf(o / lt);
}

extern "C" void kernel_launch(void* const* d_in, const int* in_sizes, int n_in,
                              void* d_out, int out_size, void* d_ws, size_t ws_size,
                              hipStream_t stream){
  const float* x       = (const float*)d_in[0];
  const float* freqs   = (const float*)d_in[1];
  const float* k_cache = (const float*)d_in[2];
  const float* v_cache = (const float*)d_in[3];
  const float* Wq = (const float*)d_in[4];
  const float* bq = (const float*)d_in[5];
  const float* Wk = (const float*)d_in[6];
  const float* bk = (const float*)d_in[7];
  const float* Wv = (const float*)d_in[8];
  const float* bv = (const float*)d_in[9];
  const float* Wo = (const float*)d_in[10];
  const float* bo = (const float*)d_in[11];
  const float* gq = (const float*)d_in[12];
  const float* gk = (const float*)d_in[13];
  const int*   cur = (const int*)d_in[14];

  const int S = in_sizes[0] / DIMN;
  const int CACHE_ = in_sizes[2] / DIMN;
  const int L = CACHE_ + S;
  const int CLn = L - S;

  auto al = [](size_t n){ return (n + 255) & ~(size_t)255; };
  char* base = (char*)d_ws;
  size_t off = 0;
  auto take = [&](size_t n){ char* r = base + off; off += al(n); return r; };
  // persistent through attn+combine:
  unsigned short* xb  = (unsigned short*)take((size_t)S*DIMN*2);
  unsigned short* Wob = (unsigned short*)take((size_t)DIMN*DIMN*2);
  unsigned short* qb  = (unsigned short*)take((size_t)NH*S*HDIM*2);
  unsigned short* kb  = (unsigned short*)take((size_t)NH*L*HDIM*2);
  unsigned short* vtb = (unsigned short*)take((size_t)NH*HDIM*L*2);
  unsigned short* ob  = (unsigned short*)take((size_t)S*DIMN*2);
  const size_t ubase = off;
  // union pool A: transients (live until attn launch)
  const size_t lin_sz = al((size_t)S*DIMN*4);
  const size_t w_sz   = al((size_t)DIMN*DIMN*2);
  float*          lin = (float*)(base + ubase);
  unsigned short* Wqb = (unsigned short*)(base + ubase + lin_sz);
  unsigned short* Wkb = (unsigned short*)(base + ubase + lin_sz + w_sz);
  unsigned short* Wvb = (unsigned short*)(base + ubase + lin_sz + 2*w_sz);
  const size_t trans_sz = lin_sz + 3*w_sz;
  // union pool B: attention partials (live from attn to combine)
  auto pool_sz = [&](int ns){
    return al((size_t)ns*NH*S*HDIM*4) + al((size_t)ns*NH*S*2*4);
  };
  int nsplit = 1;
  if (ubase + (trans_sz > pool_sz(4) ? trans_sz : pool_sz(4)) <= ws_size) nsplit = 4;
  else if (ubase + (trans_sz > pool_sz(2) ? trans_sz : pool_sz(2)) <= ws_size) nsplit = 2;
  if (ubase + trans_sz > ws_size) return;  // cannot run at all
  float* pacc = (float*)(base + ubase);
  float* pml  = (float*)(base + ubase + al((size_t)nsplit*NH*S*HDIM*4));

  const int wn8 = DIMN*DIMN/8;
  cast_bf16_kernel<<<(S*DIMN/8+255)/256, 256, 0, stream>>>(x,  xb,  S*DIMN/8);
  cast_bf16_kernel<<<(wn8+255)/256, 256, 0, stream>>>(Wq, Wqb, wn8);
  cast_bf16_kernel<<<(wn8+255)/256, 256, 0, stream>>>(Wk, Wkb, wn8);
  cast_bf16_kernel<<<(wn8+255)/256, 256, 0, stream>>>(Wv, Wvb, wn8);
  cast_bf16_kernel<<<(wn8+255)/256, 256, 0, stream>>>(Wo, Wob, wn8);
  kcache_kernel<<<CACHE_, 256, 0, stream>>>(k_cache, kb, CACHE_, L);
  vtrans_kernel<<<dim3((CACHE_+63)/64, 4, NH), 256, 0, stream>>>(v_cache, vtb, CACHE_, 0, L);

  dim3 ggrid(DIMN/128, (S+127)/128);
  gemm_bt<<<ggrid, 256, 0, stream>>>(xb, Wqb, bq, lin, S, DIMN, DIMN);
  norm_rope_kernel<<<S, 256, 0, stream>>>(lin, gq, freqs, cur, qb, S, (size_t)S*HDIM, 0);
  gemm_bt<<<ggrid, 256, 0, stream>>>(xb, Wkb, bk, lin, S, DIMN, DIMN);
  norm_rope_kernel<<<S, 256, 0, stream>>>(lin, gk, freqs, cur, kb, S, (size_t)L*HDIM, CACHE_);
  gemm_bt<<<ggrid, 256, 0, stream>>>(xb, Wvb, bv, lin, S, DIMN, DIMN);
  vtrans_kernel<<<dim3((S+63)/64, 4, NH), 256, 0, stream>>>(lin, vtb, S, CACHE_, L);

  attn_kernel<<<dim3((S+127)/128, NH, nsplit), 256, 0, stream>>>(qb, kb, vtb, ob,
                                                                 pacc, pml, S, L, CLn, nsplit);
  if (nsplit > 1)
    combine_kernel<<<(S*NH+1)/2, 256, 0, stream>>>(pacc, pml, ob, S, nsplit);
  gemm_bt<<<ggrid, 256, 0, stream>>>(ob, Wob, bo, (float*)d_out, S, DIMN, DIMN);
}

// Round 4
// 646.540 us; speedup vs baseline: 2.3070x; 2.3070x over previous
//
#include <hip/hip_runtime.h>

#define DIMN 2048
#define NH 16
#define HDIM 128

typedef __attribute__((ext_vector_type(4))) float f32x4;
typedef __attribute__((ext_vector_type(8))) __bf16 bfx8;
typedef __attribute__((ext_vector_type(8))) unsigned short u16x8;

__device__ __forceinline__ unsigned short f2bf(float f){
  unsigned u = __builtin_bit_cast(unsigned, f);
  u += 0x7fffu + ((u >> 16) & 1u);
  return (unsigned short)(u >> 16);
}

__device__ __forceinline__ void gl_lds16(const void* g, void* l){
  __builtin_amdgcn_global_load_lds((const __attribute__((address_space(1))) void*)g,
                                   (__attribute__((address_space(3))) void*)l, 16, 0, 0);
}

#define MFMA16(a,b,c) __builtin_amdgcn_mfma_f32_16x16x32_bf16((a),(b),(c),0,0,0)

// ---------------- elementwise f32 -> bf16 cast ----------------
__global__ __launch_bounds__(256) void cast_bf16_kernel(const float* __restrict__ in,
                                                        unsigned short* __restrict__ out, int n8){
  int i = blockIdx.x*256 + threadIdx.x;
  if (i >= n8) return;
  const float4* p = (const float4*)(in + (size_t)i*8);
  float4 a = p[0], b = p[1];
  u16x8 o;
  o[0]=f2bf(a.x); o[1]=f2bf(a.y); o[2]=f2bf(a.z); o[3]=f2bf(a.w);
  o[4]=f2bf(b.x); o[5]=f2bf(b.y); o[6]=f2bf(b.z); o[7]=f2bf(b.w);
  *(u16x8*)(out + (size_t)i*8) = o;
}

// ---------------- k_cache (CACHE,H,HD) f32 -> kb[h][k][d] bf16 ----------------
__global__ __launch_bounds__(256) void kcache_kernel(const float* __restrict__ kc,
                                                     unsigned short* __restrict__ kb,
                                                     int R, int L_){
  const int gid = blockIdx.x*256 + threadIdx.x;
  if (gid >= R*256) return;
  const size_t idx = (size_t)gid * 8;
  const int k   = (int)(idx >> 11);
  const int rem = (int)(idx & 2047);
  const int hh  = rem >> 7, d = rem & 127;
  const float4* p = (const float4*)(kc + idx);
  float4 a = p[0], b = p[1];
  u16x8 o;
  o[0]=f2bf(a.x); o[1]=f2bf(a.y); o[2]=f2bf(a.z); o[3]=f2bf(a.w);
  o[4]=f2bf(b.x); o[5]=f2bf(b.y); o[6]=f2bf(b.z); o[7]=f2bf(b.w);
  *(u16x8*)(kb + (size_t)hh*L_*HDIM + (size_t)k*HDIM + d) = o;
}

// ---------------- (R,H,HD) f32 -> vt[h][d][koff+k] bf16 (transpose) ----------------
__global__ __launch_bounds__(256) void vtrans_kernel(const float* __restrict__ src,
                                                     unsigned short* __restrict__ vt,
                                                     int R, int koff, int L_){
  __shared__ __align__(16) unsigned short tile[32][72];
  const int kb0 = blockIdx.x * 64, db0 = blockIdx.y * 32, hh = blockIdx.z;
  const int t = threadIdx.x;
  const int kk = t >> 2, dd = (t & 3) * 8;
  const int k = kb0 + kk;
  if (k < R){
    const float* p = src + (size_t)k*DIMN + hh*HDIM + db0 + dd;
    float4 a = ((const float4*)p)[0], b = ((const float4*)p)[1];
    tile[dd+0][kk] = f2bf(a.x); tile[dd+1][kk] = f2bf(a.y);
    tile[dd+2][kk] = f2bf(a.z); tile[dd+3][kk] = f2bf(a.w);
    tile[dd+4][kk] = f2bf(b.x); tile[dd+5][kk] = f2bf(b.y);
    tile[dd+6][kk] = f2bf(b.z); tile[dd+7][kk] = f2bf(b.w);
  }
  __syncthreads();
  const int d = t >> 3, k0 = (t & 7) * 8;
  unsigned short* dst = vt + (size_t)hh*HDIM*L_ + (size_t)(db0+d)*L_ + koff + kb0 + k0;
  if (kb0 + k0 + 8 <= R){
    *(u16x8*)dst = *(const u16x8*)&tile[d][k0];
  } else {
    #pragma unroll
    for (int e=0;e<8;++e) if (kb0 + k0 + e < R) dst[e] = tile[d][k0+e];
  }
}

// ---------------- fused rmsnorm + interleaved RoPE, bf16 head-major out ----------------
__global__ __launch_bounds__(256) void norm_rope_kernel(const float* __restrict__ lin,
    const float* __restrict__ g, const float* __restrict__ freqs, const int* __restrict__ cur,
    unsigned short* __restrict__ out, int S_, size_t head_stride, int row_off){
  const int q = blockIdx.x, t = threadIdx.x;
  const float* row = lin + (size_t)q * DIMN;
  float4 v0 = ((const float4*)row)[t*2];
  float4 v1 = ((const float4*)row)[t*2+1];
  float x[8] = {v0.x, v0.y, v0.z, v0.w, v1.x, v1.y, v1.z, v1.w};
  float ss = 0.f;
  #pragma unroll
  for (int e=0;e<8;++e) ss += x[e]*x[e];
  for (int m=1;m<64;m<<=1) ss += __shfl_xor(ss, m);
  __shared__ float red[4];
  if ((t & 63) == 0) red[t>>6] = ss;
  __syncthreads();
  const float tot = red[0]+red[1]+red[2]+red[3];
  const float rstd = rsqrtf(tot * (1.0f/2048.0f) + 1e-6f);
  const int n0 = t*8;
  float xr[8];
  #pragma unroll
  for (int e=0;e<8;++e) xr[e] = x[e] * rstd * g[n0+e];
  const int pos = cur[0] + q;
  const int hh = n0 >> 7, d0 = n0 & 127;
  const float* fr = freqs + (size_t)pos * HDIM;
  float o[8];
  #pragma unroll
  for (int p=0;p<4;++p){
    const int j = (d0>>1) + p;
    const float c = fr[j], s = fr[64+j];
    o[2*p]   = xr[2*p]*c - xr[2*p+1]*s;
    o[2*p+1] = xr[2*p+1]*c + xr[2*p]*s;
  }
  u16x8 ov;
  #pragma unroll
  for (int e=0;e<8;++e) ov[e] = f2bf(o[e]);
  *(u16x8*)(out + (size_t)hh*head_stride + (size_t)(q+row_off)*HDIM + d0) = ov;
}

// ---------------- C[M,N] = A[M,K] * B[N,K]^T + bias, bf16 in fp32 out ----------------
__global__ __launch_bounds__(256,2) void gemm_bt(const unsigned short* __restrict__ A,
    const unsigned short* __restrict__ B, const float* __restrict__ bias,
    float* __restrict__ C, int M, int N, int K){
  __shared__ __align__(16) unsigned short As[128*64];
  __shared__ __align__(16) unsigned short Bs[128*64];
  const int t = threadIdx.x;
  const int w = t >> 6, lane = t & 63, lh = lane >> 4, ll = lane & 15;
  const int wr = w >> 1, wc = w & 1;
  const int m0 = blockIdx.y * 128, n0 = blockIdx.x * 128;
  const int srow = t >> 3;
  const int scb  = (t & 7) * 16;
  const int swc  = (scb ^ ((srow & 7) << 4)) >> 1;
  int arow[4]; size_t brow[4];
  #pragma unroll
  for (int c=0;c<4;++c){
    int r = m0 + c*32 + srow; if (r >= M) r = M-1;
    arow[c] = r;
    brow[c] = (size_t)(n0 + c*32 + srow);
  }
  const int xsw = (ll & 7) << 4;
  f32x4 acc[4][4] = {};
  const int nk = K >> 6;
  for (int kt = 0; kt < nk; ++kt){
    const int k0 = kt << 6;
    #pragma unroll
    for (int c=0;c<4;++c){
      gl_lds16(A + (size_t)arow[c]*K + k0 + swc, (char*)As + c*4096 + w*1024);
      gl_lds16(B + brow[c]*K       + k0 + swc, (char*)Bs + c*4096 + w*1024);
    }
    asm volatile("s_waitcnt vmcnt(0)" ::: "memory");
    __syncthreads();
    #pragma unroll
    for (int kk=0;kk<2;++kk){
      const int cb = kk*64 + lh*16;
      bfx8 a[4], b[4];
      #pragma unroll
      for (int i=0;i<4;++i)
        a[i] = *(const bfx8*)((const char*)As + (wr*64 + i*16 + ll)*128 + (cb ^ xsw));
      #pragma unroll
      for (int j=0;j<4;++j)
        b[j] = *(const bfx8*)((const char*)Bs + (wc*64 + j*16 + ll)*128 + (cb ^ xsw));
      #pragma unroll
      for (int i=0;i<4;++i)
        #pragma unroll
        for (int j=0;j<4;++j)
          acc[i][j] = MFMA16(a[i], b[j], acc[i][j]);
    }
    __syncthreads();
  }
  #pragma unroll
  for (int i=0;i<4;++i){
    #pragma unroll
    for (int j=0;j<4;++j){
      const int col = n0 + wc*64 + j*16 + ll;
      const float bb = bias[col];
      #pragma unroll
      for (int r=0;r<4;++r){
        const int row = m0 + wr*64 + i*16 + lh*4 + r;
        if (row < M) C[(size_t)row*N + col] = acc[i][j][r] + bb;
      }
    }
  }
}

// ---------------- flash attention with KV-split partials ----------------
// 4 waves, 128 q-rows/block, 64-key tiles, blockIdx.z = KV split index.
// LDS 32KB (P overlays each wave's quarter of Ks after QK^T; extra barrier).
// launch_bounds (256,2): R3's (256,4) capped VGPR at 64 -> acc spilled to
// scratch (4GB HBM traffic). 128 VGPR still allows 4 blocks/CU.
__global__ __launch_bounds__(256,2) void attn_kernel(const unsigned short* __restrict__ Q,
    const unsigned short* __restrict__ K, const unsigned short* __restrict__ VT,
    unsigned short* __restrict__ O, float* __restrict__ pacc, float* __restrict__ pml,
    int S_, int L_, int CLn, int nsplit){
  __shared__ __align__(16) unsigned short Ks[64*128];
  __shared__ __align__(16) unsigned short Vs[128*64];
  const int hh = blockIdx.y;
  const int q0 = blockIdx.x * 128;
  const int z  = blockIdx.z;
  const int t = threadIdx.x, w = t >> 6, lane = t & 63, lh = lane >> 4, ll = lane & 15;
  const int xsw = (ll & 7) << 4;
  char* Pw = (char*)Ks + w*4096;     // wave-private P buffer overlaying Ks quarter
  const unsigned short* Qh = Q  + (size_t)hh*S_*HDIM;
  const unsigned short* Kh = K  + (size_t)hh*L_*HDIM;
  const unsigned short* Vh = VT + (size_t)hh*HDIM*L_;
  bfx8 qf[2][4];
  #pragma unroll
  for (int i=0;i<2;++i){
    int qr = q0 + w*32 + i*16 + ll; if (qr >= S_) qr = S_ - 1;
    #pragma unroll
    for (int kk=0;kk<4;++kk)
      qf[i][kk] = *(const bfx8*)(Qh + (size_t)qr*HDIM + kk*32 + lh*8);
  }
  f32x4 acc[2][8] = {};
  float m_st[2][4], l_st[2][4];
  #pragma unroll
  for (int i=0;i<2;++i)
    #pragma unroll
    for (int r=0;r<4;++r){ m_st[i][r] = -1e20f; l_st[i][r] = 0.f; }
  const int wrow0 = q0 + w*32;
  int qlast = q0 + 127; if (qlast >= S_) qlast = S_ - 1;
  const int kend = CLn + qlast + 1;
  const int nt = (kend + 63) >> 6;
  const int tps = (nt + nsplit - 1) / nsplit;
  const int t0 = z * tps;
  int t1 = t0 + tps; if (t1 > nt) t1 = nt;
  const float scale = 0.08838834764831845f;
  const int ksrow = t >> 4, kchunk = t & 15;
  const int vsrow = t >> 3, vchunk = t & 7;

  for (int kt = t0; kt < t1; ++kt){
    const int kv0 = kt << 6;
    u16x8 kreg[4], vreg[4];
    #pragma unroll
    for (int c=0;c<4;++c){
      int krow = kv0 + c*16 + ksrow; if (krow >= L_) krow = L_ - 1;
      kreg[c] = *(const u16x8*)(Kh + (size_t)krow*HDIM + kchunk*8);
      int vcol = kv0 + vchunk*8; if (vcol > L_ - 8) vcol = L_ - 8;
      vreg[c] = *(const u16x8*)(Vh + (size_t)(c*32 + vsrow)*L_ + vcol);
    }
    __syncthreads();   // all waves done reading prev tile's Ks(P)/Vs
    #pragma unroll
    for (int c=0;c<4;++c){
      *(u16x8*)((char*)Ks + (c*16 + ksrow)*256 + ((kchunk*16) ^ ((ksrow & 7) << 4))) = kreg[c];
      *(u16x8*)((char*)Vs + (c*32 + vsrow)*128 + ((vchunk*16) ^ ((vsrow & 7) << 4))) = vreg[c];
    }
    __syncthreads();
    // QK^T
    f32x4 sc[2][4] = {};
    #pragma unroll
    for (int kk=0;kk<4;++kk){
      const int cb = kk*64 + lh*16;
      #pragma unroll
      for (int j=0;j<4;++j){
        bfx8 kf = *(const bfx8*)((const char*)Ks + (j*16 + ll)*256 + (cb ^ xsw));
        sc[0][j] = MFMA16(qf[0][kk], kf, sc[0][j]);
        sc[1][j] = MFMA16(qf[1][kk], kf, sc[1][j]);
      }
    }
    // scale + causal mask
    const bool needmask = (kv0 + 63 > CLn + wrow0);
    #pragma unroll
    for (int i=0;i<2;++i)
      #pragma unroll
      for (int j=0;j<4;++j)
        #pragma unroll
        for (int r=0;r<4;++r){
          float v = sc[i][j][r] * scale;
          if (needmask){
            const int qrow = wrow0 + i*16 + lh*4 + r;
            const int key  = kv0 + j*16 + ll;
            if (key > CLn + qrow) v = -1e30f;
          }
          sc[i][j][r] = v;
        }
    // row max (floored) + defer-max decision
    float pmax[2][4];
    float mdiff = 0.f;
    #pragma unroll
    for (int i=0;i<2;++i){
      #pragma unroll
      for (int r=0;r<4;++r){
        float m = fmaxf(fmaxf(sc[i][0][r], sc[i][1][r]), fmaxf(sc[i][2][r], sc[i][3][r]));
        m = fmaxf(m, __shfl_xor(m, 1));
        m = fmaxf(m, __shfl_xor(m, 2));
        m = fmaxf(m, __shfl_xor(m, 4));
        m = fmaxf(m, __shfl_xor(m, 8));
        m = fmaxf(m, -1e20f);
        pmax[i][r] = m;
        mdiff = fmaxf(mdiff, m - m_st[i][r]);
      }
    }
    const bool skip = __all(mdiff <= 8.0f);
    if (!skip){
      #pragma unroll
      for (int i=0;i<2;++i){
        #pragma unroll
        for (int r=0;r<4;++r){
          const float mn = fmaxf(m_st[i][r], pmax[i][r]);
          const float corr = __expf(m_st[i][r] - mn);
          m_st[i][r] = mn;
          l_st[i][r] *= corr;
          #pragma unroll
          for (int jn=0;jn<8;++jn) acc[i][jn][r] *= corr;
        }
      }
    }
    // P = exp(sc - m), row-sum
    #pragma unroll
    for (int i=0;i<2;++i){
      #pragma unroll
      for (int r=0;r<4;++r){
        float rs = 0.f;
        #pragma unroll
        for (int j=0;j<4;++j){
          const float pv = __expf(sc[i][j][r] - m_st[i][r]);
          sc[i][j][r] = pv;
          rs += pv;
        }
        rs += __shfl_xor(rs, 1);
        rs += __shfl_xor(rs, 2);
        rs += __shfl_xor(rs, 4);
        rs += __shfl_xor(rs, 8);
        l_st[i][r] += rs;
      }
    }
    __syncthreads();   // all waves done reading K data from Ks; P may overlay
    #pragma unroll
    for (int i=0;i<2;++i)
      #pragma unroll
      for (int j=0;j<4;++j)
        #pragma unroll
        for (int r=0;r<4;++r){
          const int prow = i*16 + lh*4 + r;
          const int pcb  = (j*16 + ll)*2;
          *(unsigned short*)(Pw + prow*128 + (pcb ^ ((prow & 7) << 4))) = f2bf(sc[i][j][r]);
        }
    // PV
    #pragma unroll
    for (int kk=0;kk<2;++kk){
      const int cb = kk*64 + lh*16;
      bfx8 af0 = *(const bfx8*)(Pw + (ll)*128      + (cb ^ xsw));
      bfx8 af1 = *(const bfx8*)(Pw + (16 + ll)*128 + (cb ^ xsw));
      #pragma unroll
      for (int jn=0;jn<8;++jn){
        bfx8 vf = *(const bfx8*)((const char*)Vs + (jn*16 + ll)*128 + (cb ^ xsw));
        acc[0][jn] = MFMA16(af0, vf, acc[0][jn]);
        acc[1][jn] = MFMA16(af1, vf, acc[1][jn]);
      }
    }
  }
  // epilogue
  if (nsplit == 1){
    #pragma unroll
    for (int i=0;i<2;++i){
      #pragma unroll
      for (int r=0;r<4;++r){
        const float inv = 1.0f / l_st[i][r];
        const int qr = wrow0 + i*16 + lh*4 + r;
        if (qr < S_){
          #pragma unroll
          for (int jn=0;jn<8;++jn)
            O[(size_t)qr*DIMN + hh*HDIM + jn*16 + ll] = f2bf(acc[i][jn][r]*inv);
        }
      }
    }
  } else {
    #pragma unroll
    for (int i=0;i<2;++i){
      #pragma unroll
      for (int r=0;r<4;++r){
        const int qr = wrow0 + i*16 + lh*4 + r;
        if (qr < S_){
          const size_t rid = ((size_t)z*NH + hh)*S_ + qr;
          float* dst = pacc + rid*128;
          #pragma unroll
          for (int jn=0;jn<8;++jn) dst[jn*16 + ll] = acc[i][jn][r];
          if (ll == 0){
            pml[rid*2]   = m_st[i][r];
            pml[rid*2+1] = l_st[i][r];
          }
        }
      }
    }
  }
}

// ---------------- combine partials -> ob bf16 ----------------
__global__ __launch_bounds__(256) void combine_kernel(const float* __restrict__ pacc,
    const float* __restrict__ pml, unsigned short* __restrict__ ob, int S_, int nsplit){
  const int t = threadIdx.x;
  const int rid = blockIdx.x*2 + (t >> 7);   // hh*S_+q
  if (rid >= S_*NH) return;
  const int d = t & 127;
  const int hh = rid / S_;
  const int q  = rid - hh*S_;
  float M = -1e20f;
  for (int s=0; s<nsplit; ++s)
    M = fmaxf(M, pml[((size_t)s*NH*S_ + rid)*2]);
  float lt = 0.f, o = 0.f;
  for (int s=0; s<nsplit; ++s){
    const float m = pml[((size_t)s*NH*S_ + rid)*2];
    const float l = pml[((size_t)s*NH*S_ + rid)*2 + 1];
    const float wgt = __expf(m - M);
    lt += l * wgt;
    o  += pacc[((size_t)s*NH*S_ + rid)*128 + d] * wgt;
  }
  if (lt == 0.f) lt = 1.f;
  ob[(size_t)q*DIMN + hh*HDIM + d] = f2bf(o / lt);
}

extern "C" void kernel_launch(void* const* d_in, const int* in_sizes, int n_in,
                              void* d_out, int out_size, void* d_ws, size_t ws_size,
                              hipStream_t stream){
  const float* x       = (const float*)d_in[0];
  const float* freqs   = (const float*)d_in[1];
  const float* k_cache = (const float*)d_in[2];
  const float* v_cache = (const float*)d_in[3];
  const float* Wq = (const float*)d_in[4];
  const float* bq = (const float*)d_in[5];
  const float* Wk = (const float*)d_in[6];
  const float* bk = (const float*)d_in[7];
  const float* Wv = (const float*)d_in[8];
  const float* bv = (const float*)d_in[9];
  const float* Wo = (const float*)d_in[10];
  const float* bo = (const float*)d_in[11];
  const float* gq = (const float*)d_in[12];
  const float* gk = (const float*)d_in[13];
  const int*   cur = (const int*)d_in[14];

  const int S = in_sizes[0] / DIMN;
  const int CACHE_ = in_sizes[2] / DIMN;
  const int L = CACHE_ + S;
  const int CLn = L - S;

  auto al = [](size_t n){ return (n + 255) & ~(size_t)255; };
  char* base = (char*)d_ws;
  size_t off = 0;
  auto take = [&](size_t n){ char* r = base + off; off += al(n); return r; };
  // persistent through attn+combine:
  unsigned short* xb  = (unsigned short*)take((size_t)S*DIMN*2);
  unsigned short* Wob = (unsigned short*)take((size_t)DIMN*DIMN*2);
  unsigned short* qb  = (unsigned short*)take((size_t)NH*S*HDIM*2);
  unsigned short* kb  = (unsigned short*)take((size_t)NH*L*HDIM*2);
  unsigned short* vtb = (unsigned short*)take((size_t)NH*HDIM*L*2);
  unsigned short* ob  = (unsigned short*)take((size_t)S*DIMN*2);
  const size_t ubase = off;
  // union pool A: transients (live until attn launch)
  const size_t lin_sz = al((size_t)S*DIMN*4);
  const size_t w_sz   = al((size_t)DIMN*DIMN*2);
  float*          lin = (float*)(base + ubase);
  unsigned short* Wqb = (unsigned short*)(base + ubase + lin_sz);
  unsigned short* Wkb = (unsigned short*)(base + ubase + lin_sz + w_sz);
  unsigned short* Wvb = (unsigned short*)(base + ubase + lin_sz + 2*w_sz);
  const size_t trans_sz = lin_sz + 3*w_sz;
  // union pool B: attention partials (live from attn to combine)
  auto pool_sz = [&](int ns){
    return al((size_t)ns*NH*S*HDIM*4) + al((size_t)ns*NH*S*2*4);
  };
  int nsplit = 1;
  if (ubase + (trans_sz > pool_sz(4) ? trans_sz : pool_sz(4)) <= ws_size) nsplit = 4;
  else if (ubase + (trans_sz > pool_sz(2) ? trans_sz : pool_sz(2)) <= ws_size) nsplit = 2;
  if (ubase + trans_sz > ws_size) return;  // cannot run at all
  float* pacc = (float*)(base + ubase);
  float* pml  = (float*)(base + ubase + al((size_t)nsplit*NH*S*HDIM*4));

  const int wn8 = DIMN*DIMN/8;
  cast_bf16_kernel<<<(S*DIMN/8+255)/256, 256, 0, stream>>>(x,  xb,  S*DIMN/8);
  cast_bf16_kernel<<<(wn8+255)/256, 256, 0, stream>>>(Wq, Wqb, wn8);
  cast_bf16_kernel<<<(wn8+255)/256, 256, 0, stream>>>(Wk, Wkb, wn8);
  cast_bf16_kernel<<<(wn8+255)/256, 256, 0, stream>>>(Wv, Wvb, wn8);
  cast_bf16_kernel<<<(wn8+255)/256, 256, 0, stream>>>(Wo, Wob, wn8);
  kcache_kernel<<<CACHE_, 256, 0, stream>>>(k_cache, kb, CACHE_, L);
  vtrans_kernel<<<dim3((CACHE_+63)/64, 4, NH), 256, 0, stream>>>(v_cache, vtb, CACHE_, 0, L);

  dim3 ggrid(DIMN/128, (S+127)/128);
  gemm_bt<<<ggrid, 256, 0, stream>>>(xb, Wqb, bq, lin, S, DIMN, DIMN);
  norm_rope_kernel<<<S, 256, 0, stream>>>(lin, gq, freqs, cur, qb, S, (size_t)S*HDIM, 0);
  gemm_bt<<<ggrid, 256, 0, stream>>>(xb, Wkb, bk, lin, S, DIMN, DIMN);
  norm_rope_kernel<<<S, 256, 0, stream>>>(lin, gk, freqs, cur, kb, S, (size_t)L*HDIM, CACHE_);
  gemm_bt<<<ggrid, 256, 0, stream>>>(xb, Wvb, bv, lin, S, DIMN, DIMN);
  vtrans_kernel<<<dim3((S+63)/64, 4, NH), 256, 0, stream>>>(lin, vtb, S, CACHE_, L);

  attn_kernel<<<dim3((S+127)/128, NH, nsplit), 256, 0, stream>>>(qb, kb, vtb, ob,
                                                                 pacc, pml, S, L, CLn, nsplit);
  if (nsplit > 1)
    combine_kernel<<<(S*NH+1)/2, 256, 0, stream>>>(pacc, pml, ob, S, nsplit);
  gemm_bt<<<ggrid, 256, 0, stream>>>(ob, Wob, bo, (float*)d_out, S, DIMN, DIMN);
}

// Round 5
// 534.606 us; speedup vs baseline: 2.7901x; 1.2094x over previous
//
#include <hip/hip_runtime.h>

#define DIMN 2048
#define NH 16
#define HDIM 128

typedef __attribute__((ext_vector_type(4))) float f32x4;
typedef __attribute__((ext_vector_type(8))) __bf16 bfx8;
typedef __attribute__((ext_vector_type(8))) unsigned short u16x8;
typedef __attribute__((ext_vector_type(4))) unsigned short u16x4;

__device__ __forceinline__ unsigned short f2bf(float f){
  unsigned u = __builtin_bit_cast(unsigned, f);
  u += 0x7fffu + ((u >> 16) & 1u);
  return (unsigned short)(u >> 16);
}

__device__ __forceinline__ void gl_lds16(const void* g, void* l){
  __builtin_amdgcn_global_load_lds((const __attribute__((address_space(1))) void*)g,
                                   (__attribute__((address_space(3))) void*)l, 16, 0, 0);
}

#define MFMA16(a,b,c) __builtin_amdgcn_mfma_f32_16x16x32_bf16((a),(b),(c),0,0,0)

// ---------------- elementwise f32 -> bf16 cast ----------------
__global__ __launch_bounds__(256) void cast_bf16_kernel(const float* __restrict__ in,
                                                        unsigned short* __restrict__ out, int n8){
  int i = blockIdx.x*256 + threadIdx.x;
  if (i >= n8) return;
  const float4* p = (const float4*)(in + (size_t)i*8);
  float4 a = p[0], b = p[1];
  u16x8 o;
  o[0]=f2bf(a.x); o[1]=f2bf(a.y); o[2]=f2bf(a.z); o[3]=f2bf(a.w);
  o[4]=f2bf(b.x); o[5]=f2bf(b.y); o[6]=f2bf(b.z); o[7]=f2bf(b.w);
  *(u16x8*)(out + (size_t)i*8) = o;
}

// ---------------- k_cache (CACHE,H,HD) f32 -> kb[h][k][d] bf16 ----------------
__global__ __launch_bounds__(256) void kcache_kernel(const float* __restrict__ kc,
                                                     unsigned short* __restrict__ kb,
                                                     int R, int L_){
  const int gid = blockIdx.x*256 + threadIdx.x;
  if (gid >= R*256) return;
  const size_t idx = (size_t)gid * 8;
  const int k   = (int)(idx >> 11);
  const int rem = (int)(idx & 2047);
  const int hh  = rem >> 7, d = rem & 127;
  const float4* p = (const float4*)(kc + idx);
  float4 a = p[0], b = p[1];
  u16x8 o;
  o[0]=f2bf(a.x); o[1]=f2bf(a.y); o[2]=f2bf(a.z); o[3]=f2bf(a.w);
  o[4]=f2bf(b.x); o[5]=f2bf(b.y); o[6]=f2bf(b.z); o[7]=f2bf(b.w);
  *(u16x8*)(kb + (size_t)hh*L_*HDIM + (size_t)k*HDIM + d) = o;
}

// ---------------- (R,H,HD) f32 -> vt[h][d][koff+k] bf16 (transpose) ----------------
__global__ __launch_bounds__(256) void vtrans_kernel(const float* __restrict__ src,
                                                     unsigned short* __restrict__ vt,
                                                     int R, int koff, int L_){
  __shared__ __align__(16) unsigned short tile[32][72];
  const int kb0 = blockIdx.x * 64, db0 = blockIdx.y * 32, hh = blockIdx.z;
  const int t = threadIdx.x;
  const int kk = t >> 2, dd = (t & 3) * 8;
  const int k = kb0 + kk;
  if (k < R){
    const float* p = src + (size_t)k*DIMN + hh*HDIM + db0 + dd;
    float4 a = ((const float4*)p)[0], b = ((const float4*)p)[1];
    tile[dd+0][kk] = f2bf(a.x); tile[dd+1][kk] = f2bf(a.y);
    tile[dd+2][kk] = f2bf(a.z); tile[dd+3][kk] = f2bf(a.w);
    tile[dd+4][kk] = f2bf(b.x); tile[dd+5][kk] = f2bf(b.y);
    tile[dd+6][kk] = f2bf(b.z); tile[dd+7][kk] = f2bf(b.w);
  }
  __syncthreads();
  const int d = t >> 3, k0 = (t & 7) * 8;
  unsigned short* dst = vt + (size_t)hh*HDIM*L_ + (size_t)(db0+d)*L_ + koff + kb0 + k0;
  if (kb0 + k0 + 8 <= R){
    *(u16x8*)dst = *(const u16x8*)&tile[d][k0];
  } else {
    #pragma unroll
    for (int e=0;e<8;++e) if (kb0 + k0 + e < R) dst[e] = tile[d][k0+e];
  }
}

// ---------------- fused rmsnorm + interleaved RoPE, bf16 head-major out ----------------
__global__ __launch_bounds__(256) void norm_rope_kernel(const float* __restrict__ lin,
    const float* __restrict__ g, const float* __restrict__ freqs, const int* __restrict__ cur,
    unsigned short* __restrict__ out, int S_, size_t head_stride, int row_off){
  const int q = blockIdx.x, t = threadIdx.x;
  const float* row = lin + (size_t)q * DIMN;
  float4 v0 = ((const float4*)row)[t*2];
  float4 v1 = ((const float4*)row)[t*2+1];
  float x[8] = {v0.x, v0.y, v0.z, v0.w, v1.x, v1.y, v1.z, v1.w};
  float ss = 0.f;
  #pragma unroll
  for (int e=0;e<8;++e) ss += x[e]*x[e];
  for (int m=1;m<64;m<<=1) ss += __shfl_xor(ss, m);
  __shared__ float red[4];
  if ((t & 63) == 0) red[t>>6] = ss;
  __syncthreads();
  const float tot = red[0]+red[1]+red[2]+red[3];
  const float rstd = rsqrtf(tot * (1.0f/2048.0f) + 1e-6f);
  const int n0 = t*8;
  float xr[8];
  #pragma unroll
  for (int e=0;e<8;++e) xr[e] = x[e] * rstd * g[n0+e];
  const int pos = cur[0] + q;
  const int hh = n0 >> 7, d0 = n0 & 127;
  const float* fr = freqs + (size_t)pos * HDIM;
  float o[8];
  #pragma unroll
  for (int p=0;p<4;++p){
    const int j = (d0>>1) + p;
    const float c = fr[j], s = fr[64+j];
    o[2*p]   = xr[2*p]*c - xr[2*p+1]*s;
    o[2*p+1] = xr[2*p+1]*c + xr[2*p]*s;
  }
  u16x8 ov;
  #pragma unroll
  for (int e=0;e<8;++e) ov[e] = f2bf(o[e]);
  *(u16x8*)(out + (size_t)hh*head_stride + (size_t)(q+row_off)*HDIM + d0) = ov;
}

// ---------------- C[M,N] = A[M,K] * B[N,K]^T + bias, bf16 in fp32 out ----------------
__global__ __launch_bounds__(256,2) void gemm_bt(const unsigned short* __restrict__ A,
    const unsigned short* __restrict__ B, const float* __restrict__ bias,
    float* __restrict__ C, int M, int N, int K){
  __shared__ __align__(16) unsigned short As[128*64];
  __shared__ __align__(16) unsigned short Bs[128*64];
  const int t = threadIdx.x;
  const int w = t >> 6, lane = t & 63, lh = lane >> 4, ll = lane & 15;
  const int wr = w >> 1, wc = w & 1;
  const int m0 = blockIdx.y * 128, n0 = blockIdx.x * 128;
  const int srow = t >> 3;
  const int scb  = (t & 7) * 16;
  const int swc  = (scb ^ ((srow & 7) << 4)) >> 1;
  int arow[4]; size_t brow[4];
  #pragma unroll
  for (int c=0;c<4;++c){
    int r = m0 + c*32 + srow; if (r >= M) r = M-1;
    arow[c] = r;
    brow[c] = (size_t)(n0 + c*32 + srow);
  }
  const int xsw = (ll & 7) << 4;
  f32x4 acc[4][4] = {};
  const int nk = K >> 6;
  for (int kt = 0; kt < nk; ++kt){
    const int k0 = kt << 6;
    #pragma unroll
    for (int c=0;c<4;++c){
      gl_lds16(A + (size_t)arow[c]*K + k0 + swc, (char*)As + c*4096 + w*1024);
      gl_lds16(B + brow[c]*K       + k0 + swc, (char*)Bs + c*4096 + w*1024);
    }
    asm volatile("s_waitcnt vmcnt(0)" ::: "memory");
    __syncthreads();
    #pragma unroll
    for (int kk=0;kk<2;++kk){
      const int cb = kk*64 + lh*16;
      bfx8 a[4], b[4];
      #pragma unroll
      for (int i=0;i<4;++i)
        a[i] = *(const bfx8*)((const char*)As + (wr*64 + i*16 + ll)*128 + (cb ^ xsw));
      #pragma unroll
      for (int j=0;j<4;++j)
        b[j] = *(const bfx8*)((const char*)Bs + (wc*64 + j*16 + ll)*128 + (cb ^ xsw));
      #pragma unroll
      for (int i=0;i<4;++i)
        #pragma unroll
        for (int j=0;j<4;++j)
          acc[i][j] = MFMA16(a[i], b[j], acc[i][j]);
    }
    __syncthreads();
  }
  #pragma unroll
  for (int i=0;i<4;++i){
    #pragma unroll
    for (int j=0;j<4;++j){
      const int col = n0 + wc*64 + j*16 + ll;
      const float bb = bias[col];
      #pragma unroll
      for (int r=0;r<4;++r){
        const int row = m0 + wr*64 + i*16 + lh*4 + r;
        if (row < M) C[(size_t)row*N + col] = acc[i][j][r] + bb;
      }
    }
  }
}

// ---------------- flash attention with KV-split partials ----------------
// 4 waves, 128 q-rows/block, 64-key tiles, blockIdx.z = KV split index.
// SWAPPED QK^T: sc = mfma(K,Q) -> C[row=k][col=q], each lane owns q-row (q=ll):
//   softmax = in-lane reduce over 16 regs + 2 shfl_xor (vs 64 shfl before).
// P-store: r-consecutive k's -> u16x4 ds_write_b64 (8 stores vs 32).
// T14 prefetch: next tile's K/V global->reg loads issued before compute.
// State (m,l) in q=ll view; rescale/epilogue transpose to acc view via bpermute.
__global__ __launch_bounds__(256,2) void attn_kernel(const unsigned short* __restrict__ Q,
    const unsigned short* __restrict__ K, const unsigned short* __restrict__ VT,
    unsigned short* __restrict__ O, float* __restrict__ pacc, float* __restrict__ pml,
    int S_, int L_, int CLn, int nsplit){
  __shared__ __align__(16) unsigned short Ks[64*128];
  __shared__ __align__(16) unsigned short Vs[128*64];
  const int hh = blockIdx.y;
  const int q0 = blockIdx.x * 128;
  const int z  = blockIdx.z;
  const int t = threadIdx.x, w = t >> 6, lane = t & 63, lh = lane >> 4, ll = lane & 15;
  const int xsw = (ll & 7) << 4;
  char* Pw = (char*)Ks + w*4096;     // wave-private P buffer overlaying Ks quarter
  const unsigned short* Qh = Q  + (size_t)hh*S_*HDIM;
  const unsigned short* Kh = K  + (size_t)hh*L_*HDIM;
  const unsigned short* Vh = VT + (size_t)hh*HDIM*L_;
  bfx8 qf[2][4];
  #pragma unroll
  for (int i=0;i<2;++i){
    int qr = q0 + w*32 + i*16 + ll; if (qr >= S_) qr = S_ - 1;
    #pragma unroll
    for (int kk=0;kk<4;++kk)
      qf[i][kk] = *(const bfx8*)(Qh + (size_t)qr*HDIM + kk*32 + lh*8);
  }
  f32x4 acc[2][8] = {};
  float m_st[2], l_st[2];
  m_st[0] = m_st[1] = -1e20f;
  l_st[0] = l_st[1] = 0.f;
  const int wrow0 = q0 + w*32;
  int qlast = q0 + 127; if (qlast >= S_) qlast = S_ - 1;
  const int kend = CLn + qlast + 1;
  const int nt = (kend + 63) >> 6;
  const int tps = (nt + nsplit - 1) / nsplit;
  const int t0 = z * tps;
  int t1 = t0 + tps; if (t1 > nt) t1 = nt;
  const float scale = 0.08838834764831845f;
  const int ksrow = t >> 4, kchunk = t & 15;
  const int vsrow = t >> 3, vchunk = t & 7;
  const int myq[2] = { wrow0 + ll, wrow0 + 16 + ll };   // this lane's q-rows (state view)

  u16x8 kreg[4], vreg[4];
  auto load_tile = [&](int ktile){
    const int kv0 = ktile << 6;
    #pragma unroll
    for (int c=0;c<4;++c){
      int krow = kv0 + c*16 + ksrow; if (krow >= L_) krow = L_ - 1;
      kreg[c] = *(const u16x8*)(Kh + (size_t)krow*HDIM + kchunk*8);
      int vcol = kv0 + vchunk*8; if (vcol > L_ - 8) vcol = L_ - 8;
      vreg[c] = *(const u16x8*)(Vh + (size_t)(c*32 + vsrow)*L_ + vcol);
    }
  };
  if (t0 < t1) load_tile(t0);

  for (int kt = t0; kt < t1; ++kt){
    const int kv0 = kt << 6;
    __syncthreads();   // all waves done reading prev tile's Ks(P)/Vs
    #pragma unroll
    for (int c=0;c<4;++c){
      *(u16x8*)((char*)Ks + (c*16 + ksrow)*256 + ((kchunk*16) ^ ((ksrow & 7) << 4))) = kreg[c];
      *(u16x8*)((char*)Vs + (c*32 + vsrow)*128 + ((vchunk*16) ^ ((vsrow & 7) << 4))) = vreg[c];
    }
    __syncthreads();
    if (kt + 1 < t1) load_tile(kt + 1);   // T14: hide HBM latency under compute
    // QK^T (swapped): sc[i][j] -> C[row=k_sub=lh*4+r (+j*16)][col=q=ll (+i*16)]
    f32x4 sc[2][4] = {};
    #pragma unroll
    for (int kk=0;kk<4;++kk){
      const int cb = kk*64 + lh*16;
      #pragma unroll
      for (int j=0;j<4;++j){
        bfx8 kf = *(const bfx8*)((const char*)Ks + (j*16 + ll)*256 + (cb ^ xsw));
        sc[0][j] = MFMA16(kf, qf[0][kk], sc[0][j]);
        sc[1][j] = MFMA16(kf, qf[1][kk], sc[1][j]);
      }
    }
    // scale + causal mask (key depends on j,r; qrow on i only)
    const bool needmask = (kv0 + 63 > CLn + wrow0);
    if (needmask){
      #pragma unroll
      for (int i=0;i<2;++i){
        const int lim = CLn + myq[i];
        #pragma unroll
        for (int j=0;j<4;++j)
          #pragma unroll
          for (int r=0;r<4;++r){
            const int key = kv0 + j*16 + lh*4 + r;
            sc[i][j][r] = (key > lim) ? -1e30f : sc[i][j][r]*scale;
          }
      }
    } else {
      #pragma unroll
      for (int i=0;i<2;++i)
        #pragma unroll
        for (int j=0;j<4;++j)
          #pragma unroll
          for (int r=0;r<4;++r) sc[i][j][r] *= scale;
    }
    // row max: in-lane 16 + cross-replica (xor16, xor32)
    float m_t[2];
    #pragma unroll
    for (int i=0;i<2;++i){
      float mt = sc[i][0][0];
      #pragma unroll
      for (int j=0;j<4;++j)
        #pragma unroll
        for (int r=0;r<4;++r) mt = fmaxf(mt, sc[i][j][r]);
      mt = fmaxf(mt, __shfl_xor(mt, 16));
      mt = fmaxf(mt, __shfl_xor(mt, 32));
      m_t[i] = fmaxf(mt, -1e20f);
    }
    const float mdiff = fmaxf(m_t[0] - m_st[0], m_t[1] - m_st[1]);
    if (!__all(mdiff <= 8.0f)){
      float corr[2];
      #pragma unroll
      for (int i=0;i<2;++i){
        const float mn = fmaxf(m_st[i], m_t[i]);
        corr[i] = __expf(m_st[i] - mn);
        m_st[i] = mn;
        l_st[i] *= corr[i];
      }
      // transpose corr (q=ll view) -> acc view (q=lh*4+r)
      #pragma unroll
      for (int i=0;i<2;++i)
        #pragma unroll
        for (int r=0;r<4;++r){
          const float ca = __shfl(corr[i], lh*4 + r);
          #pragma unroll
          for (int jn=0;jn<8;++jn) acc[i][jn][r] *= ca;
        }
    }
    // P = exp(sc - m), in-lane sum + cross-replica sum
    #pragma unroll
    for (int i=0;i<2;++i){
      float rs = 0.f;
      #pragma unroll
      for (int j=0;j<4;++j)
        #pragma unroll
        for (int r=0;r<4;++r){
          const float pv = __expf(sc[i][j][r] - m_st[i]);
          sc[i][j][r] = pv;
          rs += pv;
        }
      rs += __shfl_xor(rs, 16);
      rs += __shfl_xor(rs, 32);
      l_st[i] += rs;
    }
    __syncthreads();   // all waves done reading Ks as K; P may overlay
    // P-store: row = i*16+ll (q), col k = j*16+lh*4+r -> packed b64 writes
    #pragma unroll
    for (int i=0;i<2;++i)
      #pragma unroll
      for (int j=0;j<4;++j){
        u16x4 pk;
        #pragma unroll
        for (int r=0;r<4;++r) pk[r] = f2bf(sc[i][j][r]);
        *(u16x4*)(Pw + (i*16 + ll)*128 + ((j*32 + lh*8) ^ xsw)) = pk;
      }
    // PV (unchanged): A = P[q][k] frag, B = V^T frag
    #pragma unroll
    for (int kk=0;kk<2;++kk){
      const int cb = kk*64 + lh*16;
      bfx8 af0 = *(const bfx8*)(Pw + (ll)*128      + (cb ^ xsw));
      bfx8 af1 = *(const bfx8*)(Pw + (16 + ll)*128 + (cb ^ xsw));
      #pragma unroll
      for (int jn=0;jn<8;++jn){
        bfx8 vf = *(const bfx8*)((const char*)Vs + (jn*16 + ll)*128 + (cb ^ xsw));
        acc[0][jn] = MFMA16(af0, vf, acc[0][jn]);
        acc[1][jn] = MFMA16(af1, vf, acc[1][jn]);
      }
    }
  }
  // epilogue
  if (nsplit == 1){
    #pragma unroll
    for (int i=0;i<2;++i){
      const float linv = 1.0f / l_st[i];
      #pragma unroll
      for (int r=0;r<4;++r){
        const float inv = __shfl(linv, lh*4 + r);
        const int qr = wrow0 + i*16 + lh*4 + r;
        if (qr < S_){
          #pragma unroll
          for (int jn=0;jn<8;++jn)
            O[(size_t)qr*DIMN + hh*HDIM + jn*16 + ll] = f2bf(acc[i][jn][r]*inv);
        }
      }
    }
  } else {
    #pragma unroll
    for (int i=0;i<2;++i){
      #pragma unroll
      for (int r=0;r<4;++r){
        const int qr = wrow0 + i*16 + lh*4 + r;
        if (qr < S_){
          const size_t rid = ((size_t)z*NH + hh)*S_ + qr;
          float* dst = pacc + rid*128;
          #pragma unroll
          for (int jn=0;jn<8;++jn) dst[jn*16 + ll] = acc[i][jn][r];
        }
      }
      // m,l stored from state view (lanes 0-15 own q = wrow0+i*16+ll)
      if (lane < 16){
        const int qr2 = myq[i];
        if (qr2 < S_){
          const size_t rid2 = ((size_t)z*NH + hh)*S_ + qr2;
          pml[rid2*2]   = m_st[i];
          pml[rid2*2+1] = l_st[i];
        }
      }
    }
  }
}

// ---------------- combine partials -> ob bf16 ----------------
__global__ __launch_bounds__(256) void combine_kernel(const float* __restrict__ pacc,
    const float* __restrict__ pml, unsigned short* __restrict__ ob, int S_, int nsplit){
  const int t = threadIdx.x;
  const int rid = blockIdx.x*2 + (t >> 7);   // hh*S_+q
  if (rid >= S_*NH) return;
  const int d = t & 127;
  const int hh = rid / S_;
  const int q  = rid - hh*S_;
  float M = -1e20f;
  for (int s=0; s<nsplit; ++s)
    M = fmaxf(M, pml[((size_t)s*NH*S_ + rid)*2]);
  float lt = 0.f, o = 0.f;
  for (int s=0; s<nsplit; ++s){
    const float m = pml[((size_t)s*NH*S_ + rid)*2];
    const float l = pml[((size_t)s*NH*S_ + rid)*2 + 1];
    const float wgt = __expf(m - M);
    lt += l * wgt;
    o  += pacc[((size_t)s*NH*S_ + rid)*128 + d] * wgt;
  }
  if (lt == 0.f) lt = 1.f;
  ob[(size_t)q*DIMN + hh*HDIM + d] = f2bf(o / lt);
}

extern "C" void kernel_launch(void* const* d_in, const int* in_sizes, int n_in,
                              void* d_out, int out_size, void* d_ws, size_t ws_size,
                              hipStream_t stream){
  const float* x       = (const float*)d_in[0];
  const float* freqs   = (const float*)d_in[1];
  const float* k_cache = (const float*)d_in[2];
  const float* v_cache = (const float*)d_in[3];
  const float* Wq = (const float*)d_in[4];
  const float* bq = (const float*)d_in[5];
  const float* Wk = (const float*)d_in[6];
  const float* bk = (const float*)d_in[7];
  const float* Wv = (const float*)d_in[8];
  const float* bv = (const float*)d_in[9];
  const float* Wo = (const float*)d_in[10];
  const float* bo = (const float*)d_in[11];
  const float* gq = (const float*)d_in[12];
  const float* gk = (const float*)d_in[13];
  const int*   cur = (const int*)d_in[14];

  const int S = in_sizes[0] / DIMN;
  const int CACHE_ = in_sizes[2] / DIMN;
  const int L = CACHE_ + S;
  const int CLn = L - S;

  auto al = [](size_t n){ return (n + 255) & ~(size_t)255; };
  char* base = (char*)d_ws;
  size_t off = 0;
  auto take = [&](size_t n){ char* r = base + off; off += al(n); return r; };
  // persistent through attn+combine:
  unsigned short* xb  = (unsigned short*)take((size_t)S*DIMN*2);
  unsigned short* Wob = (unsigned short*)take((size_t)DIMN*DIMN*2);
  unsigned short* qb  = (unsigned short*)take((size_t)NH*S*HDIM*2);
  unsigned short* kb  = (unsigned short*)take((size_t)NH*L*HDIM*2);
  unsigned short* vtb = (unsigned short*)take((size_t)NH*HDIM*L*2);
  unsigned short* ob  = (unsigned short*)take((size_t)S*DIMN*2);
  const size_t ubase = off;
  // union pool A: transients (live until attn launch)
  const size_t lin_sz = al((size_t)S*DIMN*4);
  const size_t w_sz   = al((size_t)DIMN*DIMN*2);
  float*          lin = (float*)(base + ubase);
  unsigned short* Wqb = (unsigned short*)(base + ubase + lin_sz);
  unsigned short* Wkb = (unsigned short*)(base + ubase + lin_sz + w_sz);
  unsigned short* Wvb = (unsigned short*)(base + ubase + lin_sz + 2*w_sz);
  const size_t trans_sz = lin_sz + 3*w_sz;
  // union pool B: attention partials (live from attn to combine)
  auto pool_sz = [&](int ns){
    return al((size_t)ns*NH*S*HDIM*4) + al((size_t)ns*NH*S*2*4);
  };
  int nsplit = 1;
  if (ubase + (trans_sz > pool_sz(4) ? trans_sz : pool_sz(4)) <= ws_size) nsplit = 4;
  else if (ubase + (trans_sz > pool_sz(2) ? trans_sz : pool_sz(2)) <= ws_size) nsplit = 2;
  if (ubase + trans_sz > ws_size) return;  // cannot run at all
  float* pacc = (float*)(base + ubase);
  float* pml  = (float*)(base + ubase + al((size_t)nsplit*NH*S*HDIM*4));

  const int wn8 = DIMN*DIMN/8;
  cast_bf16_kernel<<<(S*DIMN/8+255)/256, 256, 0, stream>>>(x,  xb,  S*DIMN/8);
  cast_bf16_kernel<<<(wn8+255)/256, 256, 0, stream>>>(Wq, Wqb, wn8);
  cast_bf16_kernel<<<(wn8+255)/256, 256, 0, stream>>>(Wk, Wkb, wn8);
  cast_bf16_kernel<<<(wn8+255)/256, 256, 0, stream>>>(Wv, Wvb, wn8);
  cast_bf16_kernel<<<(wn8+255)/256, 256, 0, stream>>>(Wo, Wob, wn8);
  kcache_kernel<<<CACHE_, 256, 0, stream>>>(k_cache, kb, CACHE_, L);
  vtrans_kernel<<<dim3((CACHE_+63)/64, 4, NH), 256, 0, stream>>>(v_cache, vtb, CACHE_, 0, L);

  dim3 ggrid(DIMN/128, (S+127)/128);
  gemm_bt<<<ggrid, 256, 0, stream>>>(xb, Wqb, bq, lin, S, DIMN, DIMN);
  norm_rope_kernel<<<S, 256, 0, stream>>>(lin, gq, freqs, cur, qb, S, (size_t)S*HDIM, 0);
  gemm_bt<<<ggrid, 256, 0, stream>>>(xb, Wkb, bk, lin, S, DIMN, DIMN);
  norm_rope_kernel<<<S, 256, 0, stream>>>(lin, gk, freqs, cur, kb, S, (size_t)L*HDIM, CACHE_);
  gemm_bt<<<ggrid, 256, 0, stream>>>(xb, Wvb, bv, lin, S, DIMN, DIMN);
  vtrans_kernel<<<dim3((S+63)/64, 4, NH), 256, 0, stream>>>(lin, vtb, S, CACHE_, L);

  attn_kernel<<<dim3((S+127)/128, NH, nsplit), 256, 0, stream>>>(qb, kb, vtb, ob,
                                                                 pacc, pml, S, L, CLn, nsplit);
  if (nsplit > 1)
    combine_kernel<<<(S*NH+1)/2, 256, 0, stream>>>(pacc, pml, ob, S, nsplit);
  gemm_bt<<<ggrid, 256, 0, stream>>>(ob, Wob, bo, (float*)d_out, S, DIMN, DIMN);
}

// Round 6
// 504.502 us; speedup vs baseline: 2.9565x; 1.0597x over previous
//
#include <hip/hip_runtime.h>

#define DIMN 2048
#define NH 16
#define HDIM 128

typedef __attribute__((ext_vector_type(4))) float f32x4;
typedef __attribute__((ext_vector_type(8))) __bf16 bfx8;
typedef __attribute__((ext_vector_type(8))) unsigned short u16x8;
typedef __attribute__((ext_vector_type(4))) unsigned short u16x4;

__device__ __forceinline__ unsigned short f2bf(float f){
  unsigned u = __builtin_bit_cast(unsigned, f);
  u += 0x7fffu + ((u >> 16) & 1u);
  return (unsigned short)(u >> 16);
}
__device__ __forceinline__ float bf2f(unsigned short h){
  unsigned u = (unsigned)h << 16;
  return __builtin_bit_cast(float, u);
}

__device__ __forceinline__ void gl_lds16(const void* g, void* l){
  __builtin_amdgcn_global_load_lds((const __attribute__((address_space(1))) void*)g,
                                   (__attribute__((address_space(3))) void*)l, 16, 0, 0);
}

#define MFMA16(a,b,c) __builtin_amdgcn_mfma_f32_16x16x32_bf16((a),(b),(c),0,0,0)

// ---------------- elementwise f32 -> bf16 cast ----------------
__global__ __launch_bounds__(256) void cast_bf16_kernel(const float* __restrict__ in,
                                                        unsigned short* __restrict__ out, int n8){
  int i = blockIdx.x*256 + threadIdx.x;
  if (i >= n8) return;
  const float4* p = (const float4*)(in + (size_t)i*8);
  float4 a = p[0], b = p[1];
  u16x8 o;
  o[0]=f2bf(a.x); o[1]=f2bf(a.y); o[2]=f2bf(a.z); o[3]=f2bf(a.w);
  o[4]=f2bf(b.x); o[5]=f2bf(b.y); o[6]=f2bf(b.z); o[7]=f2bf(b.w);
  *(u16x8*)(out + (size_t)i*8) = o;
}

// ---------------- k_cache (CACHE,H,HD) f32 -> kb[h][k][d] bf16 ----------------
__global__ __launch_bounds__(256) void kcache_kernel(const float* __restrict__ kc,
                                                     unsigned short* __restrict__ kb,
                                                     int R, int L_){
  const int gid = blockIdx.x*256 + threadIdx.x;
  if (gid >= R*256) return;
  const size_t idx = (size_t)gid * 8;
  const int k   = (int)(idx >> 11);
  const int rem = (int)(idx & 2047);
  const int hh  = rem >> 7, d = rem & 127;
  const float4* p = (const float4*)(kc + idx);
  float4 a = p[0], b = p[1];
  u16x8 o;
  o[0]=f2bf(a.x); o[1]=f2bf(a.y); o[2]=f2bf(a.z); o[3]=f2bf(a.w);
  o[4]=f2bf(b.x); o[5]=f2bf(b.y); o[6]=f2bf(b.z); o[7]=f2bf(b.w);
  *(u16x8*)(kb + (size_t)hh*L_*HDIM + (size_t)k*HDIM + d) = o;
}

// ---------------- (R,H,HD) f32 -> vt[h][d][koff+k] bf16 (transpose) ----------------
__global__ __launch_bounds__(256) void vtrans_kernel(const float* __restrict__ src,
                                                     unsigned short* __restrict__ vt,
                                                     int R, int koff, int L_){
  __shared__ __align__(16) unsigned short tile[32][72];
  const int kb0 = blockIdx.x * 64, db0 = blockIdx.y * 32, hh = blockIdx.z;
  const int t = threadIdx.x;
  const int kk = t >> 2, dd = (t & 3) * 8;
  const int k = kb0 + kk;
  if (k < R){
    const float* p = src + (size_t)k*DIMN + hh*HDIM + db0 + dd;
    float4 a = ((const float4*)p)[0], b = ((const float4*)p)[1];
    tile[dd+0][kk] = f2bf(a.x); tile[dd+1][kk] = f2bf(a.y);
    tile[dd+2][kk] = f2bf(a.z); tile[dd+3][kk] = f2bf(a.w);
    tile[dd+4][kk] = f2bf(b.x); tile[dd+5][kk] = f2bf(b.y);
    tile[dd+6][kk] = f2bf(b.z); tile[dd+7][kk] = f2bf(b.w);
  }
  __syncthreads();
  const int d = t >> 3, k0 = (t & 7) * 8;
  unsigned short* dst = vt + (size_t)hh*HDIM*L_ + (size_t)(db0+d)*L_ + koff + kb0 + k0;
  if (kb0 + k0 + 8 <= R){
    *(u16x8*)dst = *(const u16x8*)&tile[d][k0];
  } else {
    #pragma unroll
    for (int e=0;e<8;++e) if (kb0 + k0 + e < R) dst[e] = tile[d][k0+e];
  }
}

// ---------------- same but bf16 source (projected V) ----------------
__global__ __launch_bounds__(256) void vtrans_bf16_kernel(const unsigned short* __restrict__ src,
    unsigned short* __restrict__ vt, int R, int koff, int L_){
  __shared__ __align__(16) unsigned short tile[32][72];
  const int kb0 = blockIdx.x * 64, db0 = blockIdx.y * 32, hh = blockIdx.z;
  const int t = threadIdx.x;
  const int kk = t >> 2, dd = (t & 3) * 8;
  const int k = kb0 + kk;
  if (k < R){
    u16x8 a = *(const u16x8*)(src + (size_t)k*DIMN + hh*HDIM + db0 + dd);
    #pragma unroll
    for (int e=0;e<8;++e) tile[dd+e][kk] = a[e];
  }
  __syncthreads();
  const int d = t >> 3, k0 = (t & 7) * 8;
  unsigned short* dst = vt + (size_t)hh*HDIM*L_ + (size_t)(db0+d)*L_ + koff + kb0 + k0;
  if (kb0 + k0 + 8 <= R){
    *(u16x8*)dst = *(const u16x8*)&tile[d][k0];
  } else {
    #pragma unroll
    for (int e=0;e<8;++e) if (kb0 + k0 + e < R) dst[e] = tile[d][k0+e];
  }
}

// ---------------- fused rmsnorm + interleaved RoPE (bf16 in), bf16 head-major out ----
__global__ __launch_bounds__(256) void norm_rope_kernel(const unsigned short* __restrict__ lin,
    const float* __restrict__ g, const float* __restrict__ freqs, const int* __restrict__ cur,
    unsigned short* __restrict__ out, int S_, size_t head_stride, int row_off){
  const int q = blockIdx.x, t = threadIdx.x;
  u16x8 v = *(const u16x8*)(lin + (size_t)q*DIMN + t*8);
  float x[8];
  #pragma unroll
  for (int e=0;e<8;++e) x[e] = bf2f(v[e]);
  float ss = 0.f;
  #pragma unroll
  for (int e=0;e<8;++e) ss += x[e]*x[e];
  for (int m=1;m<64;m<<=1) ss += __shfl_xor(ss, m);
  __shared__ float red[4];
  if ((t & 63) == 0) red[t>>6] = ss;
  __syncthreads();
  const float tot = red[0]+red[1]+red[2]+red[3];
  const float rstd = rsqrtf(tot * (1.0f/2048.0f) + 1e-6f);
  const int n0 = t*8;
  float xr[8];
  #pragma unroll
  for (int e=0;e<8;++e) xr[e] = x[e] * rstd * g[n0+e];
  const int pos = cur[0] + q;
  const int hh = n0 >> 7, d0 = n0 & 127;
  const float* fr = freqs + (size_t)pos * HDIM;
  float o[8];
  #pragma unroll
  for (int p=0;p<4;++p){
    const int j = (d0>>1) + p;
    const float c = fr[j], s = fr[64+j];
    o[2*p]   = xr[2*p]*c - xr[2*p+1]*s;
    o[2*p+1] = xr[2*p+1]*c + xr[2*p]*s;
  }
  u16x8 ov;
  #pragma unroll
  for (int e=0;e<8;++e) ov[e] = f2bf(o[e]);
  *(u16x8*)(out + (size_t)hh*head_stride + (size_t)(q+row_off)*HDIM + d0) = ov;
}

// ---------------- C[M,N] = A[M,K] * B[N,K]^T + bias, bf16 in fp32 out ----------------
__global__ __launch_bounds__(256,2) void gemm_bt(const unsigned short* __restrict__ A,
    const unsigned short* __restrict__ B, const float* __restrict__ bias,
    float* __restrict__ C, int M, int N, int K){
  __shared__ __align__(16) unsigned short As[128*64];
  __shared__ __align__(16) unsigned short Bs[128*64];
  const int t = threadIdx.x;
  const int w = t >> 6, lane = t & 63, lh = lane >> 4, ll = lane & 15;
  const int wr = w >> 1, wc = w & 1;
  const int m0 = blockIdx.y * 128, n0 = blockIdx.x * 128;
  const int srow = t >> 3;
  const int scb  = (t & 7) * 16;
  const int swc  = (scb ^ ((srow & 7) << 4)) >> 1;
  int arow[4]; size_t brow[4];
  #pragma unroll
  for (int c=0;c<4;++c){
    int r = m0 + c*32 + srow; if (r >= M) r = M-1;
    arow[c] = r;
    brow[c] = (size_t)(n0 + c*32 + srow);
  }
  const int xsw = (ll & 7) << 4;
  f32x4 acc[4][4] = {};
  const int nk = K >> 6;
  for (int kt = 0; kt < nk; ++kt){
    const int k0 = kt << 6;
    #pragma unroll
    for (int c=0;c<4;++c){
      gl_lds16(A + (size_t)arow[c]*K + k0 + swc, (char*)As + c*4096 + w*1024);
      gl_lds16(B + brow[c]*K       + k0 + swc, (char*)Bs + c*4096 + w*1024);
    }
    asm volatile("s_waitcnt vmcnt(0)" ::: "memory");
    __syncthreads();
    #pragma unroll
    for (int kk=0;kk<2;++kk){
      const int cb = kk*64 + lh*16;
      bfx8 a[4], b[4];
      #pragma unroll
      for (int i=0;i<4;++i)
        a[i] = *(const bfx8*)((const char*)As + (wr*64 + i*16 + ll)*128 + (cb ^ xsw));
      #pragma unroll
      for (int j=0;j<4;++j)
        b[j] = *(const bfx8*)((const char*)Bs + (wc*64 + j*16 + ll)*128 + (cb ^ xsw));
      #pragma unroll
      for (int i=0;i<4;++i)
        #pragma unroll
        for (int j=0;j<4;++j)
          acc[i][j] = MFMA16(a[i], b[j], acc[i][j]);
    }
    __syncthreads();
  }
  #pragma unroll
  for (int i=0;i<4;++i){
    #pragma unroll
    for (int j=0;j<4;++j){
      const int col = n0 + wc*64 + j*16 + ll;
      const float bb = bias[col];
      #pragma unroll
      for (int r=0;r<4;++r){
        const int row = m0 + wr*64 + i*16 + lh*4 + r;
        if (row < M) C[(size_t)row*N + col] = acc[i][j][r] + bb;
      }
    }
  }
}

// ---------------- fused QKV gemm: z selects weight/bias/output; bf16 out ----------------
__global__ __launch_bounds__(256,2) void gemm_qkv(const unsigned short* __restrict__ A,
    const unsigned short* __restrict__ B0, const unsigned short* __restrict__ B1,
    const unsigned short* __restrict__ B2, const float* __restrict__ g0,
    const float* __restrict__ g1, const float* __restrict__ g2,
    unsigned short* __restrict__ C0, unsigned short* __restrict__ C1,
    unsigned short* __restrict__ C2, int M, int N, int K){
  const int zz = blockIdx.z;
  const unsigned short* B = (zz==0) ? B0 : (zz==1) ? B1 : B2;
  const float* bias       = (zz==0) ? g0 : (zz==1) ? g1 : g2;
  unsigned short* C       = (zz==0) ? C0 : (zz==1) ? C1 : C2;
  __shared__ __align__(16) unsigned short As[128*64];
  __shared__ __align__(16) unsigned short Bs[128*64];
  const int t = threadIdx.x;
  const int w = t >> 6, lane = t & 63, lh = lane >> 4, ll = lane & 15;
  const int wr = w >> 1, wc = w & 1;
  const int m0 = blockIdx.y * 128, n0 = blockIdx.x * 128;
  const int srow = t >> 3;
  const int scb  = (t & 7) * 16;
  const int swc  = (scb ^ ((srow & 7) << 4)) >> 1;
  int arow[4]; size_t brow[4];
  #pragma unroll
  for (int c=0;c<4;++c){
    int r = m0 + c*32 + srow; if (r >= M) r = M-1;
    arow[c] = r;
    brow[c] = (size_t)(n0 + c*32 + srow);
  }
  const int xsw = (ll & 7) << 4;
  f32x4 acc[4][4] = {};
  const int nk = K >> 6;
  for (int kt = 0; kt < nk; ++kt){
    const int k0 = kt << 6;
    #pragma unroll
    for (int c=0;c<4;++c){
      gl_lds16(A + (size_t)arow[c]*K + k0 + swc, (char*)As + c*4096 + w*1024);
      gl_lds16(B + brow[c]*K       + k0 + swc, (char*)Bs + c*4096 + w*1024);
    }
    asm volatile("s_waitcnt vmcnt(0)" ::: "memory");
    __syncthreads();
    #pragma unroll
    for (int kk=0;kk<2;++kk){
      const int cb = kk*64 + lh*16;
      bfx8 a[4], b[4];
      #pragma unroll
      for (int i=0;i<4;++i)
        a[i] = *(const bfx8*)((const char*)As + (wr*64 + i*16 + ll)*128 + (cb ^ xsw));
      #pragma unroll
      for (int j=0;j<4;++j)
        b[j] = *(const bfx8*)((const char*)Bs + (wc*64 + j*16 + ll)*128 + (cb ^ xsw));
      #pragma unroll
      for (int i=0;i<4;++i)
        #pragma unroll
        for (int j=0;j<4;++j)
          acc[i][j] = MFMA16(a[i], b[j], acc[i][j]);
    }
    __syncthreads();
  }
  #pragma unroll
  for (int i=0;i<4;++i){
    #pragma unroll
    for (int j=0;j<4;++j){
      const int col = n0 + wc*64 + j*16 + ll;
      const float bb = bias[col];
      #pragma unroll
      for (int r=0;r<4;++r){
        const int row = m0 + wr*64 + i*16 + lh*4 + r;
        if (row < M) C[(size_t)row*N + col] = f2bf(acc[i][j][r] + bb);
      }
    }
  }
}

// ---------------- flash attention, double-buffered LDS, KV-split partials ----------------
// 4 waves, 128 q-rows/block, 64-key tiles. Swapped QK^T (lane owns q-row=ll),
// T14 load-late/write-early prefetch, double-buffered Ks/Vs -> ONE barrier/tile,
// dedicated P buffer (wave-private, no overlay barrier). LDS = 80KB.
__global__ __launch_bounds__(256,2) void attn_kernel(const unsigned short* __restrict__ Q,
    const unsigned short* __restrict__ K, const unsigned short* __restrict__ VT,
    unsigned short* __restrict__ O, float* __restrict__ pacc, float* __restrict__ pml,
    int S_, int L_, int CLn, int nsplit){
  __shared__ __align__(16) unsigned short Ks[2][64*128];
  __shared__ __align__(16) unsigned short Vs[2][128*64];
  __shared__ __align__(16) unsigned short Ps[4][32*64];
  const int hh = blockIdx.y;
  const int q0 = blockIdx.x * 128;
  const int z  = blockIdx.z;
  const int t = threadIdx.x, w = t >> 6, lane = t & 63, lh = lane >> 4, ll = lane & 15;
  const int xsw = (ll & 7) << 4;
  char* Pw = (char*)Ps[w];
  const unsigned short* Qh = Q  + (size_t)hh*S_*HDIM;
  const unsigned short* Kh = K  + (size_t)hh*L_*HDIM;
  const unsigned short* Vh = VT + (size_t)hh*HDIM*L_;
  bfx8 qf[2][4];
  #pragma unroll
  for (int i=0;i<2;++i){
    int qr = q0 + w*32 + i*16 + ll; if (qr >= S_) qr = S_ - 1;
    #pragma unroll
    for (int kk=0;kk<4;++kk)
      qf[i][kk] = *(const bfx8*)(Qh + (size_t)qr*HDIM + kk*32 + lh*8);
  }
  f32x4 acc[2][8] = {};
  float m_st[2], l_st[2];
  m_st[0] = m_st[1] = -1e20f;
  l_st[0] = l_st[1] = 0.f;
  const int wrow0 = q0 + w*32;
  int qlast = q0 + 127; if (qlast >= S_) qlast = S_ - 1;
  const int kend = CLn + qlast + 1;
  const int nt = (kend + 63) >> 6;
  const int tps = (nt + nsplit - 1) / nsplit;
  const int t0 = z * tps;
  int t1 = t0 + tps; if (t1 > nt) t1 = nt;
  const float scale = 0.08838834764831845f;
  const int ksrow = t >> 4, kchunk = t & 15;
  const int vsrow = t >> 3, vchunk = t & 7;
  const int myq[2] = { wrow0 + ll, wrow0 + 16 + ll };

  u16x8 kreg[4], vreg[4];
  auto load_tile = [&](int ktile){
    const int kv0 = ktile << 6;
    #pragma unroll
    for (int c=0;c<4;++c){
      int krow = kv0 + c*16 + ksrow; if (krow >= L_) krow = L_ - 1;
      kreg[c] = *(const u16x8*)(Kh + (size_t)krow*HDIM + kchunk*8);
      int vcol = kv0 + vchunk*8; if (vcol > L_ - 8) vcol = L_ - 8;
      vreg[c] = *(const u16x8*)(Vh + (size_t)(c*32 + vsrow)*L_ + vcol);
    }
  };
  auto stage_write = [&](int b){
    #pragma unroll
    for (int c=0;c<4;++c){
      *(u16x8*)((char*)Ks[b] + (c*16 + ksrow)*256 + ((kchunk*16) ^ ((ksrow & 7) << 4))) = kreg[c];
      *(u16x8*)((char*)Vs[b] + (c*32 + vsrow)*128 + ((vchunk*16) ^ ((vsrow & 7) << 4))) = vreg[c];
    }
  };
  // prologue: buf0 <- tile t0 ; regs <- tile t0+1
  if (t0 < t1){
    load_tile(t0);
    stage_write(0);
    if (t0 + 1 < t1) load_tile(t0 + 1);
  }
  int cur = 0;
  for (int kt = t0; kt < t1; ++kt){
    const int kv0 = kt << 6;
    __syncthreads();   // buf[cur] fully written; all waves past tile kt-1 reads
    const char* Kc = (const char*)Ks[cur];
    const char* Vc = (const char*)Vs[cur];
    // QK^T (swapped): C[row=k][col=q=ll]
    f32x4 sc[2][4] = {};
    #pragma unroll
    for (int kk=0;kk<4;++kk){
      const int cb = kk*64 + lh*16;
      #pragma unroll
      for (int j=0;j<4;++j){
        bfx8 kf = *(const bfx8*)(Kc + (j*16 + ll)*256 + (cb ^ xsw));
        sc[0][j] = MFMA16(kf, qf[0][kk], sc[0][j]);
        sc[1][j] = MFMA16(kf, qf[1][kk], sc[1][j]);
      }
    }
    // stage NEXT tile into the other buffer (readers of it all passed the barrier)
    if (kt + 1 < t1){
      stage_write(cur ^ 1);
      if (kt + 2 < t1) load_tile(kt + 2);   // load-late: covers softmax+PV+bar
    }
    // scale + causal mask
    const bool needmask = (kv0 + 63 > CLn + wrow0);
    if (needmask){
      #pragma unroll
      for (int i=0;i<2;++i){
        const int lim = CLn + myq[i];
        #pragma unroll
        for (int j=0;j<4;++j)
          #pragma unroll
          for (int r=0;r<4;++r){
            const int key = kv0 + j*16 + lh*4 + r;
            sc[i][j][r] = (key > lim) ? -1e30f : sc[i][j][r]*scale;
          }
      }
    } else {
      #pragma unroll
      for (int i=0;i<2;++i)
        #pragma unroll
        for (int j=0;j<4;++j)
          #pragma unroll
          for (int r=0;r<4;++r) sc[i][j][r] *= scale;
    }
    // row max: in-lane + xor16/xor32
    float m_t[2];
    #pragma unroll
    for (int i=0;i<2;++i){
      float mt = sc[i][0][0];
      #pragma unroll
      for (int j=0;j<4;++j)
        #pragma unroll
        for (int r=0;r<4;++r) mt = fmaxf(mt, sc[i][j][r]);
      mt = fmaxf(mt, __shfl_xor(mt, 16));
      mt = fmaxf(mt, __shfl_xor(mt, 32));
      m_t[i] = fmaxf(mt, -1e20f);
    }
    const float mdiff = fmaxf(m_t[0] - m_st[0], m_t[1] - m_st[1]);
    if (!__all(mdiff <= 8.0f)){
      float corr[2];
      #pragma unroll
      for (int i=0;i<2;++i){
        const float mn = fmaxf(m_st[i], m_t[i]);
        corr[i] = __expf(m_st[i] - mn);
        m_st[i] = mn;
        l_st[i] *= corr[i];
      }
      #pragma unroll
      for (int i=0;i<2;++i)
        #pragma unroll
        for (int r=0;r<4;++r){
          const float ca = __shfl(corr[i], lh*4 + r);
          #pragma unroll
          for (int jn=0;jn<8;++jn) acc[i][jn][r] *= ca;
        }
    }
    // P = exp(sc - m), row sums
    #pragma unroll
    for (int i=0;i<2;++i){
      float rs = 0.f;
      #pragma unroll
      for (int j=0;j<4;++j)
        #pragma unroll
        for (int r=0;r<4;++r){
          const float pv = __expf(sc[i][j][r] - m_st[i]);
          sc[i][j][r] = pv;
          rs += pv;
        }
      rs += __shfl_xor(rs, 16);
      rs += __shfl_xor(rs, 32);
      l_st[i] += rs;
    }
    // P-store (wave-private buffer; no barrier needed)
    #pragma unroll
    for (int i=0;i<2;++i)
      #pragma unroll
      for (int j=0;j<4;++j){
        u16x4 pk;
        #pragma unroll
        for (int r=0;r<4;++r) pk[r] = f2bf(sc[i][j][r]);
        *(u16x4*)(Pw + (i*16 + ll)*128 + ((j*32 + lh*8) ^ xsw)) = pk;
      }
    // PV
    #pragma unroll
    for (int kk=0;kk<2;++kk){
      const int cb = kk*64 + lh*16;
      bfx8 af0 = *(const bfx8*)(Pw + (ll)*128      + (cb ^ xsw));
      bfx8 af1 = *(const bfx8*)(Pw + (16 + ll)*128 + (cb ^ xsw));
      #pragma unroll
      for (int jn=0;jn<8;++jn){
        bfx8 vf = *(const bfx8*)(Vc + (jn*16 + ll)*128 + (cb ^ xsw));
        acc[0][jn] = MFMA16(af0, vf, acc[0][jn]);
        acc[1][jn] = MFMA16(af1, vf, acc[1][jn]);
      }
    }
    cur ^= 1;
  }
  // epilogue
  if (nsplit == 1){
    #pragma unroll
    for (int i=0;i<2;++i){
      const float linv = 1.0f / l_st[i];
      #pragma unroll
      for (int r=0;r<4;++r){
        const float inv = __shfl(linv, lh*4 + r);
        const int qr = wrow0 + i*16 + lh*4 + r;
        if (qr < S_){
          #pragma unroll
          for (int jn=0;jn<8;++jn)
            O[(size_t)qr*DIMN + hh*HDIM + jn*16 + ll] = f2bf(acc[i][jn][r]*inv);
        }
      }
    }
  } else {
    #pragma unroll
    for (int i=0;i<2;++i){
      #pragma unroll
      for (int r=0;r<4;++r){
        const int qr = wrow0 + i*16 + lh*4 + r;
        if (qr < S_){
          const size_t rid = ((size_t)z*NH + hh)*S_ + qr;
          float* dst = pacc + rid*128;
          #pragma unroll
          for (int jn=0;jn<8;++jn) dst[jn*16 + ll] = acc[i][jn][r];
        }
      }
      if (lane < 16){
        const int qr2 = myq[i];
        if (qr2 < S_){
          const size_t rid2 = ((size_t)z*NH + hh)*S_ + qr2;
          pml[rid2*2]   = m_st[i];
          pml[rid2*2+1] = l_st[i];
        }
      }
    }
  }
}

// ---------------- combine partials -> ob bf16 ----------------
__global__ __launch_bounds__(256) void combine_kernel(const float* __restrict__ pacc,
    const float* __restrict__ pml, unsigned short* __restrict__ ob, int S_, int nsplit){
  const int t = threadIdx.x;
  const int rid = blockIdx.x*2 + (t >> 7);   // hh*S_+q
  if (rid >= S_*NH) return;
  const int d = t & 127;
  const int hh = rid / S_;
  const int q  = rid - hh*S_;
  float M = -1e20f;
  for (int s=0; s<nsplit; ++s)
    M = fmaxf(M, pml[((size_t)s*NH*S_ + rid)*2]);
  float lt = 0.f, o = 0.f;
  for (int s=0; s<nsplit; ++s){
    const float m = pml[((size_t)s*NH*S_ + rid)*2];
    const float l = pml[((size_t)s*NH*S_ + rid)*2 + 1];
    const float wgt = __expf(m - M);
    lt += l * wgt;
    o  += pacc[((size_t)s*NH*S_ + rid)*128 + d] * wgt;
  }
  if (lt == 0.f) lt = 1.f;
  ob[(size_t)q*DIMN + hh*HDIM + d] = f2bf(o / lt);
}

extern "C" void kernel_launch(void* const* d_in, const int* in_sizes, int n_in,
                              void* d_out, int out_size, void* d_ws, size_t ws_size,
                              hipStream_t stream){
  const float* x       = (const float*)d_in[0];
  const float* freqs   = (const float*)d_in[1];
  const float* k_cache = (const float*)d_in[2];
  const float* v_cache = (const float*)d_in[3];
  const float* Wq = (const float*)d_in[4];
  const float* bq = (const float*)d_in[5];
  const float* Wk = (const float*)d_in[6];
  const float* bk = (const float*)d_in[7];
  const float* Wv = (const float*)d_in[8];
  const float* bv = (const float*)d_in[9];
  const float* Wo = (const float*)d_in[10];
  const float* bo = (const float*)d_in[11];
  const float* gq = (const float*)d_in[12];
  const float* gk = (const float*)d_in[13];
  const int*   cur = (const int*)d_in[14];

  const int S = in_sizes[0] / DIMN;
  const int CACHE_ = in_sizes[2] / DIMN;
  const int L = CACHE_ + S;
  const int CLn = L - S;

  auto al = [](size_t n){ return (n + 255) & ~(size_t)255; };
  char* base = (char*)d_ws;
  size_t off = 0;
  auto take = [&](size_t n){ char* r = base + off; off += al(n); return r; };
  // persistent:
  unsigned short* xb  = (unsigned short*)take((size_t)S*DIMN*2);
  unsigned short* Wob = (unsigned short*)take((size_t)DIMN*DIMN*2);
  unsigned short* qb  = (unsigned short*)take((size_t)NH*S*HDIM*2);
  unsigned short* kb  = (unsigned short*)take((size_t)NH*L*HDIM*2);
  unsigned short* vtb = (unsigned short*)take((size_t)NH*HDIM*L*2);
  unsigned short* ob  = (unsigned short*)take((size_t)S*DIMN*2);
  const size_t ubase = off;
  // union pool A: transients (dead before attn): lin0/1/2 (bf16) + Wq/Wk/Wv (bf16)
  const size_t l_sz = al((size_t)S*DIMN*2);
  const size_t w_sz = al((size_t)DIMN*DIMN*2);
  unsigned short* lin0 = (unsigned short*)(base + ubase);
  unsigned short* lin1 = (unsigned short*)(base + ubase + l_sz);
  unsigned short* lin2 = (unsigned short*)(base + ubase + 2*l_sz);
  unsigned short* Wqb  = (unsigned short*)(base + ubase + 3*l_sz);
  unsigned short* Wkb  = (unsigned short*)(base + ubase + 3*l_sz + w_sz);
  unsigned short* Wvb  = (unsigned short*)(base + ubase + 3*l_sz + 2*w_sz);
  const size_t trans_sz = 3*l_sz + 3*w_sz;
  // union pool B: attention partials
  auto pool_sz = [&](int ns){
    return al((size_t)ns*NH*S*HDIM*4) + al((size_t)ns*NH*S*2*4);
  };
  int nsplit = 1;
  if (ubase + (trans_sz > pool_sz(4) ? trans_sz : pool_sz(4)) <= ws_size) nsplit = 4;
  else if (ubase + (trans_sz > pool_sz(2) ? trans_sz : pool_sz(2)) <= ws_size) nsplit = 2;
  if (ubase + trans_sz > ws_size) return;
  float* pacc = (float*)(base + ubase);
  float* pml  = (float*)(base + ubase + al((size_t)nsplit*NH*S*HDIM*4));

  const int wn8 = DIMN*DIMN/8;
  cast_bf16_kernel<<<(S*DIMN/8+255)/256, 256, 0, stream>>>(x,  xb,  S*DIMN/8);
  cast_bf16_kernel<<<(wn8+255)/256, 256, 0, stream>>>(Wq, Wqb, wn8);
  cast_bf16_kernel<<<(wn8+255)/256, 256, 0, stream>>>(Wk, Wkb, wn8);
  cast_bf16_kernel<<<(wn8+255)/256, 256, 0, stream>>>(Wv, Wvb, wn8);
  cast_bf16_kernel<<<(wn8+255)/256, 256, 0, stream>>>(Wo, Wob, wn8);
  kcache_kernel<<<CACHE_, 256, 0, stream>>>(k_cache, kb, CACHE_, L);
  vtrans_kernel<<<dim3((CACHE_+63)/64, 4, NH), 256, 0, stream>>>(v_cache, vtb, CACHE_, 0, L);

  const int mb = (S+127)/128;
  gemm_qkv<<<dim3(DIMN/128, mb, 3), 256, 0, stream>>>(xb, Wqb, Wkb, Wvb, bq, bk, bv,
                                                      lin0, lin1, lin2, S, DIMN, DIMN);
  norm_rope_kernel<<<S, 256, 0, stream>>>(lin0, gq, freqs, cur, qb, S, (size_t)S*HDIM, 0);
  norm_rope_kernel<<<S, 256, 0, stream>>>(lin1, gk, freqs, cur, kb, S, (size_t)L*HDIM, CACHE_);
  vtrans_bf16_kernel<<<dim3((S+63)/64, 4, NH), 256, 0, stream>>>(lin2, vtb, S, CACHE_, L);

  attn_kernel<<<dim3((S+127)/128, NH, nsplit), 256, 0, stream>>>(qb, kb, vtb, ob,
                                                                 pacc, pml, S, L, CLn, nsplit);
  if (nsplit > 1)
    combine_kernel<<<(S*NH+1)/2, 256, 0, stream>>>(pacc, pml, ob, S, nsplit);
  gemm_bt<<<dim3(DIMN/128, mb), 256, 0, stream>>>(ob, Wob, bo, (float*)d_out, S, DIMN, DIMN);
}